// Round 1
// 3506.902 us; speedup vs baseline: 1.0315x; 1.0315x over previous
//
#include <hip/hip_runtime.h>

// Problem constants
#define TSTEPS 128
#define NCLS 11
#define BTILE 8
// Re-packed weight workspace (floats):
//  WT1: [16 chunks][1024 lanes] float4, chunk = g*4+j, lane = d*8+s,
//       value = Whh1[g*128+d][4*(s+8j)+kk]
//  WT2: [12 chunks][1024 lanes] float4, chunk = g*3+j, lane = d2*16+s,
//       col = 4*(s+16j)+kk; col<128 -> Wih2 row (g*64+d2), else Whh2 col-128
#define WT1F 65536
#define WT2F 49152

__device__ __forceinline__ float sigm(float x) { return 1.0f / (1.0f + __expf(-x)); }
__device__ __forceinline__ float tanhf_(float x) { return 1.0f - 2.0f / (__expf(2.0f * x) + 1.0f); }

__global__ void prep_weights(const float* __restrict__ Whh1,
                             const float* __restrict__ Wih2,
                             const float* __restrict__ Whh2,
                             float* __restrict__ ws) {
    int idx = blockIdx.x * blockDim.x + threadIdx.x;
    if (idx < WT1F) {
        int kk = idx & 3, lane = (idx >> 2) & 1023, chunk = idx >> 12;
        int s = lane & 7, d = lane >> 3, g = chunk >> 2, j = chunk & 3;
        ws[idx] = Whh1[(g * 128 + d) * 128 + 4 * (s + 8 * j) + kk];
    } else if (idx < WT1F + WT2F) {
        int r = idx - WT1F;
        int kk = r & 3, lane = (r >> 2) & 1023, chunk = r >> 12;
        int s = lane & 15, d2 = lane >> 4, g = chunk / 3, j = chunk - 3 * g;
        int col = 4 * (s + 16 * j) + kk;
        int row = g * 64 + d2;
        ws[idx] = (col < 128) ? Wih2[row * 128 + col] : Whh2[row * 64 + (col - 128)];
    }
}

#define DOT4(acc, q, h) (acc += (q).x*(h).x + (q).y*(h).y + (q).z*(h).z + (q).w*(h).w)

// Persistent fused 2-layer LSTM + FC. grid=256 (1 block/CU), block=1024 (16 waves).
// L1 thread role: (d = tid>>3, s = tid&7). s = K-slice (k = 4*(s+8j)); after the
//   reduce-scatter, lane s owns batch row b=s -> every thread owns one (b,d) c1.
// L2 thread role: (d2 = tid>>4, s2 = tid&15), K=192 = h1(128)|h2(64); lanes s2<8
//   own (b=s2, d2) c2 and the fused FC accumulation.
// Each weight float4 is loaded from L2 exactly once per block per timestep and
// reused for all 8 batch rows in registers (8x less L2 traffic than per-(b,d)).
__global__ __launch_bounds__(1024) void lstm_fused(
    const float* __restrict__ x, const float* __restrict__ Wih1,
    const float* __restrict__ Wfc, const float* __restrict__ bfc,
    const float* __restrict__ ws, float* __restrict__ out) {

    const float4* __restrict__ w1 = (const float4*)ws;            // [16][1024]
    const float4* __restrict__ w2 = (const float4*)(ws + WT1F);   // [12][1024]

    __shared__ __align__(16) float lx[BTILE][2 * TSTEPS];  // x staged [b][c*128+t]
    __shared__ __align__(16) float lhh[BTILE][192];        // [b][0..127]=h1, [128..191]=h2
    __shared__ float fpart[16][BTILE][NCLS];               // per-wave FC partials

    const int tid = threadIdx.x;
    const int b0 = blockIdx.x * BTILE;

    for (int i = tid; i < BTILE * 2 * TSTEPS; i += 1024)
        lx[i >> 8][i & 255] = x[b0 * 256 + i];
    for (int i = tid; i < BTILE * 192; i += 1024)
        ((float*)lhh)[i] = 0.0f;

    const int d  = tid >> 3;
    const int s  = tid & 7;
    const int d2 = tid >> 4;
    const int s2 = tid & 15;

    // input-projection weights for row d (D_IN = 2), gate order i,f,g,o
    const float wia = Wih1[2 * d],           wib = Wih1[2 * d + 1];
    const float wfa = Wih1[2 * (128 + d)],   wfb = Wih1[2 * (128 + d) + 1];
    const float wga = Wih1[2 * (256 + d)],   wgb = Wih1[2 * (256 + d) + 1];
    const float woa = Wih1[2 * (384 + d)],   wob = Wih1[2 * (384 + d) + 1];

    const float4* __restrict__ w1t = w1 + tid;
    const float4* __restrict__ w2t = w2 + tid;

    float c1 = 0.0f, c2 = 0.0f;
    float facc[NCLS];
#pragma unroll
    for (int c = 0; c < NCLS; ++c) facc[c] = 0.0f;

    __syncthreads();

    for (int t = 0; t < TSTEPS; ++t) {
        // ---------------- layer 1: partial gates over K-slice s ----------------
        float v0[8], v1[8], v2[8], v3[8];
#pragma unroll
        for (int b = 0; b < 8; ++b) { v0[b] = v1[b] = v2[b] = v3[b] = 0.0f; }
#pragma unroll
        for (int j = 0; j < 4; ++j) {
            const float4 q0 = w1t[(0  + j) * 1024];   // gate i
            const float4 q1 = w1t[(4  + j) * 1024];   // gate f
            const float4 q2 = w1t[(8  + j) * 1024];   // gate g
            const float4 q3 = w1t[(12 + j) * 1024];   // gate o
            const int ko = 4 * (s + 8 * j);
#pragma unroll
            for (int b = 0; b < 8; ++b) {
                const float4 h4 = *(const float4*)&lhh[b][ko];  // 8-way broadcast, conflict-free
                DOT4(v0[b], q0, h4);
                DOT4(v1[b], q1, h4);
                DOT4(v2[b], q2, h4);
                DOT4(v3[b], q3, h4);
            }
        }
        // reduce-scatter over the 8 s-lanes (static indices only): lane s -> b = s
        const bool f4 = (s & 4) != 0;
        float A0[4], A1[4], A2[4], A3[4];
#pragma unroll
        for (int i = 0; i < 4; ++i) {
            A0[i] = (f4 ? v0[i+4] : v0[i]) + __shfl_xor(f4 ? v0[i] : v0[i+4], 4);
            A1[i] = (f4 ? v1[i+4] : v1[i]) + __shfl_xor(f4 ? v1[i] : v1[i+4], 4);
            A2[i] = (f4 ? v2[i+4] : v2[i]) + __shfl_xor(f4 ? v2[i] : v2[i+4], 4);
            A3[i] = (f4 ? v3[i+4] : v3[i]) + __shfl_xor(f4 ? v3[i] : v3[i+4], 4);
        }
        const bool f2 = (s & 2) != 0;
        float B0[2], B1[2], B2[2], B3[2];
#pragma unroll
        for (int i = 0; i < 2; ++i) {
            B0[i] = (f2 ? A0[i+2] : A0[i]) + __shfl_xor(f2 ? A0[i] : A0[i+2], 2);
            B1[i] = (f2 ? A1[i+2] : A1[i]) + __shfl_xor(f2 ? A1[i] : A1[i+2], 2);
            B2[i] = (f2 ? A2[i+2] : A2[i]) + __shfl_xor(f2 ? A2[i] : A2[i+2], 2);
            B3[i] = (f2 ? A3[i+2] : A3[i]) + __shfl_xor(f2 ? A3[i] : A3[i+2], 2);
        }
        const bool f1 = (s & 1) != 0;
        const float r0 = (f1 ? B0[1] : B0[0]) + __shfl_xor(f1 ? B0[0] : B0[1], 1);
        const float r1 = (f1 ? B1[1] : B1[0]) + __shfl_xor(f1 ? B1[0] : B1[1], 1);
        const float r2 = (f1 ? B2[1] : B2[0]) + __shfl_xor(f1 ? B2[0] : B2[1], 1);
        const float r3 = (f1 ? B3[1] : B3[0]) + __shfl_xor(f1 ? B3[0] : B3[1], 1);

        // elementwise for (b = s, d) — all 1024 threads are owners
        const float x0 = lx[s][t], x1 = lx[s][TSTEPS + t];
        const float gi = r0 + wia * x0 + wib * x1;
        const float gf = r1 + wfa * x0 + wfb * x1;
        const float gg = r2 + wga * x0 + wgb * x1;
        const float go = r3 + woa * x0 + wob * x1;
        const float i1 = sigm(gi), ff = sigm(gf), g1v = tanhf_(gg), o1 = sigm(go);
        c1 = ff * c1 + i1 * g1v;
        const float h1n = o1 * tanhf_(c1);

        __syncthreads();                 // A: all reads of old h1 done
        lhh[s][d] = h1n;
        __syncthreads();                 // B: new h1 visible

        // ---------------- layer 2: K = 192 (h1 new | h2 old), slice s2 ----------------
        float u0[8], u1[8], u2[8], u3[8];
#pragma unroll
        for (int b = 0; b < 8; ++b) { u0[b] = u1[b] = u2[b] = u3[b] = 0.0f; }
#pragma unroll
        for (int j = 0; j < 3; ++j) {
            const float4 p0 = w2t[(0 + j) * 1024];
            const float4 p1 = w2t[(3 + j) * 1024];
            const float4 p2 = w2t[(6 + j) * 1024];
            const float4 p3 = w2t[(9 + j) * 1024];
            const int ko = 4 * (s2 + 16 * j);
#pragma unroll
            for (int b = 0; b < 8; ++b) {
                const float4 h4 = *(const float4*)&lhh[b][ko];  // 4-way broadcast, conflict-free
                DOT4(u0[b], p0, h4);
                DOT4(u1[b], p1, h4);
                DOT4(u2[b], p2, h4);
                DOT4(u3[b], p3, h4);
            }
        }
        // reduce over 16 lanes: xor8 splits gate-pairs, xor4/2/1 scatter b; lane s2 -> b = s2&7
        const bool g8 = (s2 & 8) != 0;
        float U0[8], U1[8];
#pragma unroll
        for (int b = 0; b < 8; ++b) {
            U0[b] = (g8 ? u2[b] : u0[b]) + __shfl_xor(g8 ? u0[b] : u2[b], 8);
            U1[b] = (g8 ? u3[b] : u1[b]) + __shfl_xor(g8 ? u1[b] : u3[b], 8);
        }
        const bool e4 = (s2 & 4) != 0;
        float V0[4], V1[4];
#pragma unroll
        for (int i = 0; i < 4; ++i) {
            V0[i] = (e4 ? U0[i+4] : U0[i]) + __shfl_xor(e4 ? U0[i] : U0[i+4], 4);
            V1[i] = (e4 ? U1[i+4] : U1[i]) + __shfl_xor(e4 ? U1[i] : U1[i+4], 4);
        }
        const bool e2 = (s2 & 2) != 0;
        float X0[2], X1[2];
#pragma unroll
        for (int i = 0; i < 2; ++i) {
            X0[i] = (e2 ? V0[i+2] : V0[i]) + __shfl_xor(e2 ? V0[i] : V0[i+2], 2);
            X1[i] = (e2 ? V1[i+2] : V1[i]) + __shfl_xor(e2 ? V1[i] : V1[i+2], 2);
        }
        const bool e1 = (s2 & 1) != 0;
        const float D0 = (e1 ? X0[1] : X0[0]) + __shfl_xor(e1 ? X0[0] : X0[1], 1);
        const float D1 = (e1 ? X1[1] : X1[0]) + __shfl_xor(e1 ? X1[0] : X1[1], 1);
        const float E0 = __shfl_xor(D0, 8);   // other gate-pair from partner lane
        const float E1 = __shfl_xor(D1, 8);
        // on lanes s2<8: gates i=D0, f=D1, g=E0, o=E1 for b = s2

        float h2n = 0.0f;
        if (s2 < 8) {
            const float i2 = sigm(D0), f2g = sigm(D1), g2v = tanhf_(E0), o2 = sigm(E1);
            c2 = f2g * c2 + i2 * g2v;
            h2n = o2 * tanhf_(c2);
            // fused FC: out[b][c] += h2[t][d2] * Wfc[c][t*64+d2]
            const float* wfc = Wfc + t * 64 + d2;
#pragma unroll
            for (int c = 0; c < NCLS; ++c) facc[c] += h2n * wfc[c * 8192];
        }
        __syncthreads();                 // C: all h1-new / h2-old reads done
        if (s2 < 8) lhh[s2][128 + d2] = h2n;   // disjoint from next iter's h1 reads
    }

    // final FC reduction: sum facc over the 4 in-wave d2 groups (lane bits 4,5),
    // then across the 16 waves via LDS. Inactive lanes (s2>=8) hold zeros.
#pragma unroll
    for (int c = 0; c < NCLS; ++c) {
        facc[c] += __shfl_xor(facc[c], 16);
        facc[c] += __shfl_xor(facc[c], 32);
    }
    const int wv = tid >> 6;
    if ((tid & 63) < 8) {
#pragma unroll
        for (int c = 0; c < NCLS; ++c) fpart[wv][tid & 7][c] = facc[c];
    }
    __syncthreads();
    if (tid < BTILE * NCLS) {
        const int bb = tid / NCLS, c = tid - bb * NCLS;
        float v = bfc[c];
#pragma unroll
        for (int w = 0; w < 16; ++w) v += fpart[w][bb][c];
        out[(b0 + bb) * NCLS + c] = v;
    }
}

extern "C" void kernel_launch(void* const* d_in, const int* in_sizes, int n_in,
                              void* d_out, int out_size, void* d_ws, size_t ws_size,
                              hipStream_t stream) {
    const float* x    = (const float*)d_in[0];
    const float* Wih1 = (const float*)d_in[1];
    const float* Whh1 = (const float*)d_in[2];
    const float* Wih2 = (const float*)d_in[3];
    const float* Whh2 = (const float*)d_in[4];
    const float* Wfc  = (const float*)d_in[5];
    const float* bfc  = (const float*)d_in[6];
    float* out = (float*)d_out;
    float* ws  = (float*)d_ws;

    const int prep_elems = WT1F + WT2F;   // 114688 floats = 448 KB (same as before)
    prep_weights<<<(prep_elems + 255) / 256, 256, 0, stream>>>(Whh1, Wih2, Whh2, ws);
    lstm_fused<<<256, 1024, 0, stream>>>(x, Wih1, Wfc, bfc, ws, out);
}

// Round 3
// 3476.989 us; speedup vs baseline: 1.0404x; 1.0086x over previous
//
#include <hip/hip_runtime.h>

// Problem constants
#define TSTEPS 128
#define NCLS 11
#define BTILE 8
// Re-packed weight workspace (floats):
//  WT1: [16 chunks][1024 lanes] float4, chunk = g*4+j, lane = d*8+s,
//       value = Whh1[g*128+d][4*(s+8j)+kk]
//  WT2: [12 chunks][1024 lanes] float4, chunk = g*3+j, lane = d2*16+s,
//       col = 4*(s+16j)+kk; col<128 -> Wih2 row (g*64+d2), else Whh2 col-128
#define WT1F 65536
#define WT2F 49152

__device__ __forceinline__ float sigm(float x) { return 1.0f / (1.0f + __expf(-x)); }
__device__ __forceinline__ float tanhf_(float x) { return 1.0f - 2.0f / (__expf(2.0f * x) + 1.0f); }

__global__ void prep_weights(const float* __restrict__ Whh1,
                             const float* __restrict__ Wih2,
                             const float* __restrict__ Whh2,
                             float* __restrict__ ws) {
    int idx = blockIdx.x * blockDim.x + threadIdx.x;
    if (idx < WT1F) {
        int kk = idx & 3, lane = (idx >> 2) & 1023, chunk = idx >> 12;
        int s = lane & 7, d = lane >> 3, g = chunk >> 2, j = chunk & 3;
        ws[idx] = Whh1[(g * 128 + d) * 128 + 4 * (s + 8 * j) + kk];
    } else if (idx < WT1F + WT2F) {
        int r = idx - WT1F;
        int kk = r & 3, lane = (r >> 2) & 1023, chunk = r >> 12;
        int s = lane & 15, d2 = lane >> 4, g = chunk / 3, j = chunk - 3 * g;
        int col = 4 * (s + 16 * j) + kk;
        int row = g * 64 + d2;
        ws[idx] = (col < 128) ? Wih2[row * 128 + col] : Whh2[row * 64 + (col - 128)];
    }
}

#define DOT4(acc, q, h) (acc += (q).x*(h).x + (q).y*(h).y + (q).z*(h).z + (q).w*(h).w)

// Persistent fused 2-layer LSTM + FC. grid=256 (1 block/CU), block=1024 (16 waves).
// __launch_bounds__(1024, 4): 4 waves/EU == exactly our 1 persistent block/CU ->
// register allocator gets 128 VGPRs/lane. (Default budget was 64 VGPR targeting
// 2 blocks/CU we never launch -> spilled the accumulator arrays to scratch:
// 14 GB of HBM traffic, 49% of peak, round 1's whole loss.)
// L1 thread role: (d = tid>>3, s = tid&7). s = K-slice (k = 4*(s+8j)); after the
//   reduce-scatter, lane s owns batch row b=s -> every thread owns one (b,d) c1.
// L2 thread role: (d2 = tid>>4, s2 = tid&15), K=192 = h1(128)|h2(64); lanes s2<8
//   own (b=s2, d2) c2 and the fused FC accumulation.
// Each weight float4 is loaded from L2 exactly once per block per timestep and
// reused for all 8 batch rows in registers.
__global__ __launch_bounds__(1024, 4) void lstm_fused(
    const float* __restrict__ x, const float* __restrict__ Wih1,
    const float* __restrict__ Wfc, const float* __restrict__ bfc,
    const float* __restrict__ ws, float* __restrict__ out) {

    const float4* __restrict__ w1 = (const float4*)ws;            // [16][1024]
    const float4* __restrict__ w2 = (const float4*)(ws + WT1F);   // [12][1024]

    __shared__ __align__(16) float lx[BTILE][2 * TSTEPS + 4];  // +4 pad: de-bank lx[s][t] column reads
    __shared__ __align__(16) float lhh[BTILE][192];            // [b][0..127]=h1, [128..191]=h2
    __shared__ float fpart[16][BTILE][NCLS];                   // per-wave FC partials

    const int tid = threadIdx.x;
    const int b0 = blockIdx.x * BTILE;

    for (int i = tid; i < BTILE * 2 * TSTEPS; i += 1024)
        lx[i >> 8][i & 255] = x[b0 * 256 + i];
    for (int i = tid; i < BTILE * 192; i += 1024)
        ((float*)lhh)[i] = 0.0f;

    const int d  = tid >> 3;
    const int s  = tid & 7;
    const int d2 = tid >> 4;
    const int s2 = tid & 15;

    // input-projection weights for row d (D_IN = 2), gate order i,f,g,o
    const float wia = Wih1[2 * d],           wib = Wih1[2 * d + 1];
    const float wfa = Wih1[2 * (128 + d)],   wfb = Wih1[2 * (128 + d) + 1];
    const float wga = Wih1[2 * (256 + d)],   wgb = Wih1[2 * (256 + d) + 1];
    const float woa = Wih1[2 * (384 + d)],   wob = Wih1[2 * (384 + d) + 1];

    const float4* __restrict__ w1t = w1 + tid;
    const float4* __restrict__ w2t = w2 + tid;

    float c1 = 0.0f, c2 = 0.0f;
    float facc[NCLS];
#pragma unroll
    for (int c = 0; c < NCLS; ++c) facc[c] = 0.0f;

    __syncthreads();

    for (int t = 0; t < TSTEPS; ++t) {
        // ---------------- layer 1: partial gates over K-slice s ----------------
        float v0[8], v1[8], v2[8], v3[8];
#pragma unroll
        for (int b = 0; b < 8; ++b) { v0[b] = v1[b] = v2[b] = v3[b] = 0.0f; }
#pragma unroll
        for (int j = 0; j < 4; ++j) {
            const float4 q0 = w1t[(0  + j) * 1024];   // gate i
            const float4 q1 = w1t[(4  + j) * 1024];   // gate f
            const float4 q2 = w1t[(8  + j) * 1024];   // gate g
            const float4 q3 = w1t[(12 + j) * 1024];   // gate o
            const int ko = 4 * (s + 8 * j);
#pragma unroll
            for (int b = 0; b < 8; ++b) {
                const float4 h4 = *(const float4*)&lhh[b][ko];  // 8-way broadcast, conflict-free
                DOT4(v0[b], q0, h4);
                DOT4(v1[b], q1, h4);
                DOT4(v2[b], q2, h4);
                DOT4(v3[b], q3, h4);
            }
        }
        // reduce-scatter over the 8 s-lanes (static indices only): lane s -> b = s
        const bool f4 = (s & 4) != 0;
        float A0[4], A1[4], A2[4], A3[4];
#pragma unroll
        for (int i = 0; i < 4; ++i) {
            A0[i] = (f4 ? v0[i+4] : v0[i]) + __shfl_xor(f4 ? v0[i] : v0[i+4], 4);
            A1[i] = (f4 ? v1[i+4] : v1[i]) + __shfl_xor(f4 ? v1[i] : v1[i+4], 4);
            A2[i] = (f4 ? v2[i+4] : v2[i]) + __shfl_xor(f4 ? v2[i] : v2[i+4], 4);
            A3[i] = (f4 ? v3[i+4] : v3[i]) + __shfl_xor(f4 ? v3[i] : v3[i+4], 4);
        }
        const bool f2 = (s & 2) != 0;
        float B0[2], B1[2], B2[2], B3[2];
#pragma unroll
        for (int i = 0; i < 2; ++i) {
            B0[i] = (f2 ? A0[i+2] : A0[i]) + __shfl_xor(f2 ? A0[i] : A0[i+2], 2);
            B1[i] = (f2 ? A1[i+2] : A1[i]) + __shfl_xor(f2 ? A1[i] : A1[i+2], 2);
            B2[i] = (f2 ? A2[i+2] : A2[i]) + __shfl_xor(f2 ? A2[i] : A2[i+2], 2);
            B3[i] = (f2 ? A3[i+2] : A3[i]) + __shfl_xor(f2 ? A3[i] : A3[i+2], 2);
        }
        const bool f1 = (s & 1) != 0;
        const float r0 = (f1 ? B0[1] : B0[0]) + __shfl_xor(f1 ? B0[0] : B0[1], 1);
        const float r1 = (f1 ? B1[1] : B1[0]) + __shfl_xor(f1 ? B1[0] : B1[1], 1);
        const float r2 = (f1 ? B2[1] : B2[0]) + __shfl_xor(f1 ? B2[0] : B2[1], 1);
        const float r3 = (f1 ? B3[1] : B3[0]) + __shfl_xor(f1 ? B3[0] : B3[1], 1);

        // elementwise for (b = s, d) — all 1024 threads are owners
        const float x0 = lx[s][t], x1 = lx[s][TSTEPS + t];
        const float gi = r0 + wia * x0 + wib * x1;
        const float gf = r1 + wfa * x0 + wfb * x1;
        const float gg = r2 + wga * x0 + wgb * x1;
        const float go = r3 + woa * x0 + wob * x1;
        const float i1 = sigm(gi), ff = sigm(gf), g1v = tanhf_(gg), o1 = sigm(go);
        c1 = ff * c1 + i1 * g1v;
        const float h1n = o1 * tanhf_(c1);

        __syncthreads();                 // A: all reads of old h1 done
        lhh[s][d] = h1n;
        __syncthreads();                 // B: new h1 visible

        // ---------------- layer 2: K = 192 (h1 new | h2 old), slice s2 ----------------
        float u0[8], u1[8], u2[8], u3[8];
#pragma unroll
        for (int b = 0; b < 8; ++b) { u0[b] = u1[b] = u2[b] = u3[b] = 0.0f; }
#pragma unroll
        for (int j = 0; j < 3; ++j) {
            const float4 p0 = w2t[(0 + j) * 1024];
            const float4 p1 = w2t[(3 + j) * 1024];
            const float4 p2 = w2t[(6 + j) * 1024];
            const float4 p3 = w2t[(9 + j) * 1024];
            const int ko = 4 * (s2 + 16 * j);
#pragma unroll
            for (int b = 0; b < 8; ++b) {
                const float4 h4 = *(const float4*)&lhh[b][ko];  // 2-way max, free
                DOT4(u0[b], p0, h4);
                DOT4(u1[b], p1, h4);
                DOT4(u2[b], p2, h4);
                DOT4(u3[b], p3, h4);
            }
        }
        // reduce over 16 lanes: xor8 splits gate-pairs, xor4/2/1 scatter b; lane s2 -> b = s2&7
        const bool g8 = (s2 & 8) != 0;
        float U0[8], U1[8];
#pragma unroll
        for (int b = 0; b < 8; ++b) {
            U0[b] = (g8 ? u2[b] : u0[b]) + __shfl_xor(g8 ? u0[b] : u2[b], 8);
            U1[b] = (g8 ? u3[b] : u1[b]) + __shfl_xor(g8 ? u1[b] : u3[b], 8);
        }
        const bool e4 = (s2 & 4) != 0;
        float V0[4], V1[4];
#pragma unroll
        for (int i = 0; i < 4; ++i) {
            V0[i] = (e4 ? U0[i+4] : U0[i]) + __shfl_xor(e4 ? U0[i] : U0[i+4], 4);
            V1[i] = (e4 ? U1[i+4] : U1[i]) + __shfl_xor(e4 ? U1[i] : U1[i+4], 4);
        }
        const bool e2 = (s2 & 2) != 0;
        float X0[2], X1[2];
#pragma unroll
        for (int i = 0; i < 2; ++i) {
            X0[i] = (e2 ? V0[i+2] : V0[i]) + __shfl_xor(e2 ? V0[i] : V0[i+2], 2);
            X1[i] = (e2 ? V1[i+2] : V1[i]) + __shfl_xor(e2 ? V1[i] : V1[i+2], 2);
        }
        const bool e1 = (s2 & 1) != 0;
        const float D0 = (e1 ? X0[1] : X0[0]) + __shfl_xor(e1 ? X0[0] : X0[1], 1);
        const float D1 = (e1 ? X1[1] : X1[0]) + __shfl_xor(e1 ? X1[0] : X1[1], 1);
        const float E0 = __shfl_xor(D0, 8);   // other gate-pair from partner lane
        const float E1 = __shfl_xor(D1, 8);
        // on lanes s2<8: gates i=D0, f=D1, g=E0, o=E1 for b = s2

        float h2n = 0.0f;
        if (s2 < 8) {
            const float i2 = sigm(D0), f2g = sigm(D1), g2v = tanhf_(E0), o2 = sigm(E1);
            c2 = f2g * c2 + i2 * g2v;
            h2n = o2 * tanhf_(c2);
            // fused FC: out[b][c] += h2[t][d2] * Wfc[c][t*64+d2]
            const float* wfc = Wfc + t * 64 + d2;
#pragma unroll
            for (int c = 0; c < NCLS; ++c) facc[c] += h2n * wfc[c * 8192];
        }
        __syncthreads();                 // C: all h1-new / h2-old reads done
        if (s2 < 8) lhh[s2][128 + d2] = h2n;   // disjoint from next iter's h1 reads
    }

    // final FC reduction: sum facc over the 4 in-wave d2 groups (lane bits 4,5),
    // then across the 16 waves via LDS. Inactive lanes (s2>=8) hold zeros.
#pragma unroll
    for (int c = 0; c < NCLS; ++c) {
        facc[c] += __shfl_xor(facc[c], 16);
        facc[c] += __shfl_xor(facc[c], 32);
    }
    const int wv = tid >> 6;
    if ((tid & 63) < 8) {
#pragma unroll
        for (int c = 0; c < NCLS; ++c) fpart[wv][tid & 7][c] = facc[c];
    }
    __syncthreads();
    if (tid < BTILE * NCLS) {
        const int bb = tid / NCLS, c = tid - bb * NCLS;
        float v = bfc[c];
#pragma unroll
        for (int w = 0; w < 16; ++w) v += fpart[w][bb][c];
        out[(b0 + bb) * NCLS + c] = v;
    }
}

extern "C" void kernel_launch(void* const* d_in, const int* in_sizes, int n_in,
                              void* d_out, int out_size, void* d_ws, size_t ws_size,
                              hipStream_t stream) {
    const float* x    = (const float*)d_in[0];
    const float* Wih1 = (const float*)d_in[1];
    const float* Whh1 = (const float*)d_in[2];
    const float* Wih2 = (const float*)d_in[3];
    const float* Whh2 = (const float*)d_in[4];
    const float* Wfc  = (const float*)d_in[5];
    const float* bfc  = (const float*)d_in[6];
    float* out = (float*)d_out;
    float* ws  = (float*)d_ws;

    const int prep_elems = WT1F + WT2F;   // 114688 floats = 448 KB
    prep_weights<<<(prep_elems + 255) / 256, 256, 0, stream>>>(Whh1, Wih2, Whh2, ws);
    lstm_fused<<<256, 1024, 0, stream>>>(x, Wih1, Wfc, bfc, ws, out);
}

// Round 4
// 3279.814 us; speedup vs baseline: 1.1029x; 1.0601x over previous
//
#include <hip/hip_runtime.h>

// Problem constants
#define TSTEPS 128
#define NCLS 11
#define BTILE 8
// Re-packed weight workspace (floats):
//  WT1: [16 chunks][1024 lanes] float4, chunk = g*4+j, lane = d*8+s,
//       value = Whh1[g*128+d][4*(s+8j)+kk]
//  WT2: [12 chunks][1024 lanes] float4, chunk = g*3+j, lane = d2*16+s,
//       col = 4*(s+16j)+kk; col<128 -> Wih2 row (g*64+d2), else Whh2 col-128
#define WT1F 65536
#define WT2F 49152

__device__ __forceinline__ float sigm(float x) { return 1.0f / (1.0f + __expf(-x)); }
__device__ __forceinline__ float tanhf_(float x) { return 1.0f - 2.0f / (__expf(2.0f * x) + 1.0f); }

__global__ void prep_weights(const float* __restrict__ Whh1,
                             const float* __restrict__ Wih2,
                             const float* __restrict__ Whh2,
                             float* __restrict__ ws) {
    int idx = blockIdx.x * blockDim.x + threadIdx.x;
    if (idx < WT1F) {
        int kk = idx & 3, lane = (idx >> 2) & 1023, chunk = idx >> 12;
        int s = lane & 7, d = lane >> 3, g = chunk >> 2, j = chunk & 3;
        ws[idx] = Whh1[(g * 128 + d) * 128 + 4 * (s + 8 * j) + kk];
    } else if (idx < WT1F + WT2F) {
        int r = idx - WT1F;
        int kk = r & 3, lane = (r >> 2) & 1023, chunk = r >> 12;
        int s = lane & 15, d2 = lane >> 4, g = chunk / 3, j = chunk - 3 * g;
        int col = 4 * (s + 16 * j) + kk;
        int row = g * 64 + d2;
        ws[idx] = (col < 128) ? Wih2[row * 128 + col] : Whh2[row * 64 + (col - 128)];
    }
}

#define DOT4(acc, q, h) (acc += (q).x*(h).x + (q).y*(h).y + (q).z*(h).z + (q).w*(h).w)

// Persistent fused 2-layer LSTM + FC. grid=256 (1 block/CU), block=1024 (16 waves).
// amdgpu_waves_per_eu(4,4): pin occupancy to exactly 4 waves/EU (= our single
// persistent 16-wave block per CU) -> register budget 512/4 = 128 VGPRs/lane.
// (__launch_bounds__(1024,4) only sets a MINIMUM; the scheduler still targeted
// 8 waves/EU => 64 VGPR => spilled the accumulator arrays to scratch: 14 GB HBM
// round-trip at 49% of peak. VGPR_Count stayed 64 in rounds 1 and 3.)
// L1 thread role: (d = tid>>3, s = tid&7). s = K-slice (k = 4*(s+8j)); after the
//   reduce-scatter, lane s owns batch row b=s -> every thread owns one (b,d) c1.
// L2 thread role: (d2 = tid>>4, s2 = tid&15), K=192 = h1(128)|h2(64); lanes s2<8
//   own (b=s2, d2) c2 and the fused FC accumulation.
// Each weight float4 is loaded from L2 exactly once per block per timestep and
// reused for all 8 batch rows in registers.
__global__ __attribute__((amdgpu_flat_work_group_size(1024, 1024),
                          amdgpu_waves_per_eu(4, 4))) void lstm_fused(
    const float* __restrict__ x, const float* __restrict__ Wih1,
    const float* __restrict__ Wfc, const float* __restrict__ bfc,
    const float* __restrict__ ws, float* __restrict__ out) {

    const float4* __restrict__ w1 = (const float4*)ws;            // [16][1024]
    const float4* __restrict__ w2 = (const float4*)(ws + WT1F);   // [12][1024]

    __shared__ __align__(16) float lx[BTILE][2 * TSTEPS + 4];  // +4 pad: de-bank lx[s][t] column reads
    __shared__ __align__(16) float lhh[BTILE][192];            // [b][0..127]=h1, [128..191]=h2
    __shared__ float fpart[16][BTILE][NCLS];                   // per-wave FC partials

    const int tid = threadIdx.x;
    const int b0 = blockIdx.x * BTILE;

    for (int i = tid; i < BTILE * 2 * TSTEPS; i += 1024)
        lx[i >> 8][i & 255] = x[b0 * 256 + i];
    for (int i = tid; i < BTILE * 192; i += 1024)
        ((float*)lhh)[i] = 0.0f;

    const int d  = tid >> 3;
    const int s  = tid & 7;
    const int d2 = tid >> 4;
    const int s2 = tid & 15;

    // input-projection weights for row d (D_IN = 2), gate order i,f,g,o
    const float wia = Wih1[2 * d],           wib = Wih1[2 * d + 1];
    const float wfa = Wih1[2 * (128 + d)],   wfb = Wih1[2 * (128 + d) + 1];
    const float wga = Wih1[2 * (256 + d)],   wgb = Wih1[2 * (256 + d) + 1];
    const float woa = Wih1[2 * (384 + d)],   wob = Wih1[2 * (384 + d) + 1];

    const float4* __restrict__ w1t = w1 + tid;
    const float4* __restrict__ w2t = w2 + tid;

    float c1 = 0.0f, c2 = 0.0f;
    float facc[NCLS];
#pragma unroll
    for (int c = 0; c < NCLS; ++c) facc[c] = 0.0f;

    __syncthreads();

    for (int t = 0; t < TSTEPS; ++t) {
        // ---------------- layer 1: partial gates over K-slice s ----------------
        float v0[8], v1[8], v2[8], v3[8];
#pragma unroll
        for (int b = 0; b < 8; ++b) { v0[b] = v1[b] = v2[b] = v3[b] = 0.0f; }
#pragma unroll
        for (int j = 0; j < 4; ++j) {
            const float4 q0 = w1t[(0  + j) * 1024];   // gate i
            const float4 q1 = w1t[(4  + j) * 1024];   // gate f
            const float4 q2 = w1t[(8  + j) * 1024];   // gate g
            const float4 q3 = w1t[(12 + j) * 1024];   // gate o
            const int ko = 4 * (s + 8 * j);
#pragma unroll
            for (int b = 0; b < 8; ++b) {
                const float4 h4 = *(const float4*)&lhh[b][ko];  // 8-way broadcast, conflict-free
                DOT4(v0[b], q0, h4);
                DOT4(v1[b], q1, h4);
                DOT4(v2[b], q2, h4);
                DOT4(v3[b], q3, h4);
            }
        }
        // reduce-scatter over the 8 s-lanes (static indices only): lane s -> b = s
        const bool f4 = (s & 4) != 0;
        float A0[4], A1[4], A2[4], A3[4];
#pragma unroll
        for (int i = 0; i < 4; ++i) {
            A0[i] = (f4 ? v0[i+4] : v0[i]) + __shfl_xor(f4 ? v0[i] : v0[i+4], 4);
            A1[i] = (f4 ? v1[i+4] : v1[i]) + __shfl_xor(f4 ? v1[i] : v1[i+4], 4);
            A2[i] = (f4 ? v2[i+4] : v2[i]) + __shfl_xor(f4 ? v2[i] : v2[i+4], 4);
            A3[i] = (f4 ? v3[i+4] : v3[i]) + __shfl_xor(f4 ? v3[i] : v3[i+4], 4);
        }
        const bool f2 = (s & 2) != 0;
        float B0[2], B1[2], B2[2], B3[2];
#pragma unroll
        for (int i = 0; i < 2; ++i) {
            B0[i] = (f2 ? A0[i+2] : A0[i]) + __shfl_xor(f2 ? A0[i] : A0[i+2], 2);
            B1[i] = (f2 ? A1[i+2] : A1[i]) + __shfl_xor(f2 ? A1[i] : A1[i+2], 2);
            B2[i] = (f2 ? A2[i+2] : A2[i]) + __shfl_xor(f2 ? A2[i] : A2[i+2], 2);
            B3[i] = (f2 ? A3[i+2] : A3[i]) + __shfl_xor(f2 ? A3[i] : A3[i+2], 2);
        }
        const bool f1 = (s & 1) != 0;
        const float r0 = (f1 ? B0[1] : B0[0]) + __shfl_xor(f1 ? B0[0] : B0[1], 1);
        const float r1 = (f1 ? B1[1] : B1[0]) + __shfl_xor(f1 ? B1[0] : B1[1], 1);
        const float r2 = (f1 ? B2[1] : B2[0]) + __shfl_xor(f1 ? B2[0] : B2[1], 1);
        const float r3 = (f1 ? B3[1] : B3[0]) + __shfl_xor(f1 ? B3[0] : B3[1], 1);

        // elementwise for (b = s, d) — all 1024 threads are owners
        const float x0 = lx[s][t], x1 = lx[s][TSTEPS + t];
        const float gi = r0 + wia * x0 + wib * x1;
        const float gf = r1 + wfa * x0 + wfb * x1;
        const float gg = r2 + wga * x0 + wgb * x1;
        const float go = r3 + woa * x0 + wob * x1;
        const float i1 = sigm(gi), ff = sigm(gf), g1v = tanhf_(gg), o1 = sigm(go);
        c1 = ff * c1 + i1 * g1v;
        const float h1n = o1 * tanhf_(c1);

        __syncthreads();                 // A: all reads of old h1 done
        lhh[s][d] = h1n;
        __syncthreads();                 // B: new h1 visible

        // ---------------- layer 2: K = 192 (h1 new | h2 old), slice s2 ----------------
        float u0[8], u1[8], u2[8], u3[8];
#pragma unroll
        for (int b = 0; b < 8; ++b) { u0[b] = u1[b] = u2[b] = u3[b] = 0.0f; }
#pragma unroll
        for (int j = 0; j < 3; ++j) {
            const float4 p0 = w2t[(0 + j) * 1024];
            const float4 p1 = w2t[(3 + j) * 1024];
            const float4 p2 = w2t[(6 + j) * 1024];
            const float4 p3 = w2t[(9 + j) * 1024];
            const int ko = 4 * (s2 + 16 * j);
#pragma unroll
            for (int b = 0; b < 8; ++b) {
                const float4 h4 = *(const float4*)&lhh[b][ko];  // 2-way max, free
                DOT4(u0[b], p0, h4);
                DOT4(u1[b], p1, h4);
                DOT4(u2[b], p2, h4);
                DOT4(u3[b], p3, h4);
            }
        }
        // reduce over 16 lanes: xor8 splits gate-pairs, xor4/2/1 scatter b; lane s2 -> b = s2&7
        const bool g8 = (s2 & 8) != 0;
        float U0[8], U1[8];
#pragma unroll
        for (int b = 0; b < 8; ++b) {
            U0[b] = (g8 ? u2[b] : u0[b]) + __shfl_xor(g8 ? u0[b] : u2[b], 8);
            U1[b] = (g8 ? u3[b] : u1[b]) + __shfl_xor(g8 ? u1[b] : u3[b], 8);
        }
        const bool e4 = (s2 & 4) != 0;
        float V0[4], V1[4];
#pragma unroll
        for (int i = 0; i < 4; ++i) {
            V0[i] = (e4 ? U0[i+4] : U0[i]) + __shfl_xor(e4 ? U0[i] : U0[i+4], 4);
            V1[i] = (e4 ? U1[i+4] : U1[i]) + __shfl_xor(e4 ? U1[i] : U1[i+4], 4);
        }
        const bool e2 = (s2 & 2) != 0;
        float X0[2], X1[2];
#pragma unroll
        for (int i = 0; i < 2; ++i) {
            X0[i] = (e2 ? V0[i+2] : V0[i]) + __shfl_xor(e2 ? V0[i] : V0[i+2], 2);
            X1[i] = (e2 ? V1[i+2] : V1[i]) + __shfl_xor(e2 ? V1[i] : V1[i+2], 2);
        }
        const bool e1 = (s2 & 1) != 0;
        const float D0 = (e1 ? X0[1] : X0[0]) + __shfl_xor(e1 ? X0[0] : X0[1], 1);
        const float D1 = (e1 ? X1[1] : X1[0]) + __shfl_xor(e1 ? X1[0] : X1[1], 1);
        const float E0 = __shfl_xor(D0, 8);   // other gate-pair from partner lane
        const float E1 = __shfl_xor(D1, 8);
        // on lanes s2<8: gates i=D0, f=D1, g=E0, o=E1 for b = s2

        float h2n = 0.0f;
        if (s2 < 8) {
            const float i2 = sigm(D0), f2g = sigm(D1), g2v = tanhf_(E0), o2 = sigm(E1);
            c2 = f2g * c2 + i2 * g2v;
            h2n = o2 * tanhf_(c2);
            // fused FC: out[b][c] += h2[t][d2] * Wfc[c][t*64+d2]
            const float* wfc = Wfc + t * 64 + d2;
#pragma unroll
            for (int c = 0; c < NCLS; ++c) facc[c] += h2n * wfc[c * 8192];
        }
        __syncthreads();                 // C: all h1-new / h2-old reads done
        if (s2 < 8) lhh[s2][128 + d2] = h2n;   // disjoint from next iter's h1 reads
    }

    // final FC reduction: sum facc over the 4 in-wave d2 groups (lane bits 4,5),
    // then across the 16 waves via LDS. Inactive lanes (s2>=8) hold zeros.
#pragma unroll
    for (int c = 0; c < NCLS; ++c) {
        facc[c] += __shfl_xor(facc[c], 16);
        facc[c] += __shfl_xor(facc[c], 32);
    }
    const int wv = tid >> 6;
    if ((tid & 63) < 8) {
#pragma unroll
        for (int c = 0; c < NCLS; ++c) fpart[wv][tid & 7][c] = facc[c];
    }
    __syncthreads();
    if (tid < BTILE * NCLS) {
        const int bb = tid / NCLS, c = tid - bb * NCLS;
        float v = bfc[c];
#pragma unroll
        for (int w = 0; w < 16; ++w) v += fpart[w][bb][c];
        out[(b0 + bb) * NCLS + c] = v;
    }
}

extern "C" void kernel_launch(void* const* d_in, const int* in_sizes, int n_in,
                              void* d_out, int out_size, void* d_ws, size_t ws_size,
                              hipStream_t stream) {
    const float* x    = (const float*)d_in[0];
    const float* Wih1 = (const float*)d_in[1];
    const float* Whh1 = (const float*)d_in[2];
    const float* Wih2 = (const float*)d_in[3];
    const float* Whh2 = (const float*)d_in[4];
    const float* Wfc  = (const float*)d_in[5];
    const float* bfc  = (const float*)d_in[6];
    float* out = (float*)d_out;
    float* ws  = (float*)d_ws;

    const int prep_elems = WT1F + WT2F;   // 114688 floats = 448 KB
    prep_weights<<<(prep_elems + 255) / 256, 256, 0, stream>>>(Whh1, Wih2, Whh2, ws);
    lstm_fused<<<256, 1024, 0, stream>>>(x, Wih1, Wfc, bfc, ws, out);
}

// Round 5
// 2096.034 us; speedup vs baseline: 1.7258x; 1.5648x over previous
//
#include <hip/hip_runtime.h>

// Problem constants
#define TSTEPS 128
#define NCLS 11
#define BTILE 8
// Re-packed weight workspace (floats):
//  WT1: [16 chunks][1024 lanes] float4, chunk = g*4+j, lane = d*8+s,
//       value = Whh1[g*128+d][4*(s+8j)+kk]
//  WT2: [12 chunks][1024 lanes] float4, chunk = g*3+j, lane = d2*16+s,
//       col = 4*(s+16j)+kk; col<128 -> Wih2 row (g*64+d2), else Whh2 col-128
#define WT1F 65536
#define WT2F 49152

__device__ __forceinline__ float sigm(float x) { return 1.0f / (1.0f + __expf(-x)); }
__device__ __forceinline__ float tanhf_(float x) { return 1.0f - 2.0f / (__expf(2.0f * x) + 1.0f); }

__global__ void prep_weights(const float* __restrict__ Whh1,
                             const float* __restrict__ Wih2,
                             const float* __restrict__ Whh2,
                             float* __restrict__ ws) {
    int idx = blockIdx.x * blockDim.x + threadIdx.x;
    if (idx < WT1F) {
        int kk = idx & 3, lane = (idx >> 2) & 1023, chunk = idx >> 12;
        int s = lane & 7, d = lane >> 3, g = chunk >> 2, j = chunk & 3;
        ws[idx] = Whh1[(g * 128 + d) * 128 + 4 * (s + 8 * j) + kk];
    } else if (idx < WT1F + WT2F) {
        int r = idx - WT1F;
        int kk = r & 3, lane = (r >> 2) & 1023, chunk = r >> 12;
        int s = lane & 15, d2 = lane >> 4, g = chunk / 3, j = chunk - 3 * g;
        int col = 4 * (s + 16 * j) + kk;
        int row = g * 64 + d2;
        ws[idx] = (col < 128) ? Wih2[row * 128 + col] : Whh2[row * 64 + (col - 128)];
    }
}

#define DOT4(acc, q, h) (acc += (q).x*(h).x + (q).y*(h).y + (q).z*(h).z + (q).w*(h).w)

// Persistent fused 2-layer LSTM + FC. grid=256 (1 block/CU), block=1024 (16 waves).
// HARD CONSTRAINT (rounds 1-4): this toolchain pins 1024-thread kernels at a
// 64-VGPR budget (launch_bounds and waves_per_eu both failed to raise it; spills
// showed as 12.9 GB HBM round-trip at 48% peak). So the kernel is engineered to
// a <=62-reg live set:
//   - facc shrunk 11->6: upper s2-lanes (idle before) duplicate the c2/h2n
//     elementwise (their D/E regs hold the same gates swapped) and accumulate
//     FC classes 6..10; lower lanes keep classes 0..5.
//   - Wih1 input-projection weights moved to a tiny LDS table (2 float4 per d),
//     re-read each step; opaque-zero asm index blocks LICM re-hoisting.
//   - #pragma unroll 1 on the t-loop (no pressure doubling).
// L1 thread role: (d = tid>>3, s = tid&7): K-slice s; reduce-scatter -> lane s
//   owns batch b=s: every thread owns one (b,d) c1.
// L2 thread role: (d2 = tid>>4, s2 = tid&15), K=192 = h1|h2; both lane-halves
//   own (b=s2&7, d2) c2 (redundant compute, split FC classes).
__global__ __attribute__((amdgpu_flat_work_group_size(1024, 1024),
                          amdgpu_waves_per_eu(4, 4))) void lstm_fused(
    const float* __restrict__ x, const float* __restrict__ Wih1,
    const float* __restrict__ Wfc, const float* __restrict__ bfc,
    const float* __restrict__ ws, float* __restrict__ out) {

    const float4* __restrict__ w1 = (const float4*)ws;            // [16][1024]
    const float4* __restrict__ w2 = (const float4*)(ws + WT1F);   // [12][1024]

    __shared__ __align__(16) float lx[BTILE][2 * TSTEPS + 4];  // x staged [b][c*128+t]
    __shared__ __align__(16) float lhh[BTILE][192];            // [b][0..127]=h1, [128..191]=h2
    __shared__ __align__(16) float4 lwih4[2][128];             // [0][d]=(ia,ib,fa,fb) [1][d]=(ga,gb,oa,ob)
    __shared__ float fpart[16][BTILE][NCLS];                   // per-wave FC partials

    const int tid = threadIdx.x;
    const int b0 = blockIdx.x * BTILE;

    for (int i = tid; i < BTILE * 2 * TSTEPS; i += 1024)
        lx[i >> 8][i & 255] = x[b0 * 256 + i];
    for (int i = tid; i < BTILE * 192; i += 1024)
        ((float*)lhh)[i] = 0.0f;
    if (tid < 128) {
        const float2* wp = (const float2*)Wih1;   // row r -> float2 at index r
        const float2 ri = wp[tid], rf = wp[128 + tid], rg = wp[256 + tid], ro = wp[384 + tid];
        lwih4[0][tid] = make_float4(ri.x, ri.y, rf.x, rf.y);
        lwih4[1][tid] = make_float4(rg.x, rg.y, ro.x, ro.y);
    }

    const int d  = tid >> 3;
    const int s  = tid & 7;
    const int d2 = tid >> 4;
    const int s2 = tid & 15;
    const bool lowh = (s2 < 8);

    const float4* __restrict__ w1t = w1 + tid;
    const float4* __restrict__ w2t = w2 + tid;

    float c1 = 0.0f, c2 = 0.0f;
    float facc[6];
#pragma unroll
    for (int c = 0; c < 6; ++c) facc[c] = 0.0f;

    __syncthreads();

#pragma unroll 1
    for (int t = 0; t < TSTEPS; ++t) {
        // ---------------- layer 1: partial gates over K-slice s ----------------
        float v0[8], v1[8], v2[8], v3[8];
#pragma unroll
        for (int b = 0; b < 8; ++b) { v0[b] = v1[b] = v2[b] = v3[b] = 0.0f; }
#pragma unroll
        for (int j = 0; j < 4; ++j) {
            const float4 q0 = w1t[(0  + j) * 1024];   // gate i
            const float4 q1 = w1t[(4  + j) * 1024];   // gate f
            const float4 q2 = w1t[(8  + j) * 1024];   // gate g
            const float4 q3 = w1t[(12 + j) * 1024];   // gate o
            const int ko = 4 * (s + 8 * j);
#pragma unroll
            for (int b = 0; b < 8; ++b) {
                const float4 h4 = *(const float4*)&lhh[b][ko];  // 8-way broadcast, conflict-free
                DOT4(v0[b], q0, h4);
                DOT4(v1[b], q1, h4);
                DOT4(v2[b], q2, h4);
                DOT4(v3[b], q3, h4);
            }
        }
        // reduce-scatter over the 8 s-lanes (static indices only): lane s -> b = s
        const bool f4 = (s & 4) != 0;
        float A0[4], A1[4], A2[4], A3[4];
#pragma unroll
        for (int i = 0; i < 4; ++i) {
            A0[i] = (f4 ? v0[i+4] : v0[i]) + __shfl_xor(f4 ? v0[i] : v0[i+4], 4);
            A1[i] = (f4 ? v1[i+4] : v1[i]) + __shfl_xor(f4 ? v1[i] : v1[i+4], 4);
            A2[i] = (f4 ? v2[i+4] : v2[i]) + __shfl_xor(f4 ? v2[i] : v2[i+4], 4);
            A3[i] = (f4 ? v3[i+4] : v3[i]) + __shfl_xor(f4 ? v3[i] : v3[i+4], 4);
        }
        const bool f2 = (s & 2) != 0;
        float B0[2], B1[2], B2[2], B3[2];
#pragma unroll
        for (int i = 0; i < 2; ++i) {
            B0[i] = (f2 ? A0[i+2] : A0[i]) + __shfl_xor(f2 ? A0[i] : A0[i+2], 2);
            B1[i] = (f2 ? A1[i+2] : A1[i]) + __shfl_xor(f2 ? A1[i] : A1[i+2], 2);
            B2[i] = (f2 ? A2[i+2] : A2[i]) + __shfl_xor(f2 ? A2[i] : A2[i+2], 2);
            B3[i] = (f2 ? A3[i+2] : A3[i]) + __shfl_xor(f2 ? A3[i] : A3[i+2], 2);
        }
        const bool f1 = (s & 1) != 0;
        const float r0 = (f1 ? B0[1] : B0[0]) + __shfl_xor(f1 ? B0[0] : B0[1], 1);
        const float r1 = (f1 ? B1[1] : B1[0]) + __shfl_xor(f1 ? B1[0] : B1[1], 1);
        const float r2 = (f1 ? B2[1] : B2[0]) + __shfl_xor(f1 ? B2[0] : B2[1], 1);
        const float r3 = (f1 ? B3[1] : B3[0]) + __shfl_xor(f1 ? B3[0] : B3[1], 1);

        // elementwise for (b = s, d) — all 1024 threads are owners.
        // Wih1 from LDS each step; opaque zero index defeats LICM hoisting.
        int zr; asm volatile("v_mov_b32 %0, 0" : "=v"(zr));
        const float4 wv0 = lwih4[0][d + zr];
        const float4 wv1 = lwih4[1][d + zr];
        const float x0 = lx[s][t], x1 = lx[s][TSTEPS + t];
        const float gi = r0 + wv0.x * x0 + wv0.y * x1;
        const float gf = r1 + wv0.z * x0 + wv0.w * x1;
        const float gg = r2 + wv1.x * x0 + wv1.y * x1;
        const float go = r3 + wv1.z * x0 + wv1.w * x1;
        const float i1 = sigm(gi), ff = sigm(gf), g1v = tanhf_(gg), o1 = sigm(go);
        c1 = ff * c1 + i1 * g1v;
        const float h1n = o1 * tanhf_(c1);

        __syncthreads();                 // A: all reads of old h1 done
        lhh[s][d] = h1n;
        __syncthreads();                 // B: new h1 visible

        // ---------------- layer 2: K = 192 (h1 new | h2 old), slice s2 ----------------
        float u0[8], u1[8], u2[8], u3[8];
#pragma unroll
        for (int b = 0; b < 8; ++b) { u0[b] = u1[b] = u2[b] = u3[b] = 0.0f; }
#pragma unroll
        for (int j = 0; j < 3; ++j) {
            const float4 p0 = w2t[(0 + j) * 1024];
            const float4 p1 = w2t[(3 + j) * 1024];
            const float4 p2 = w2t[(6 + j) * 1024];
            const float4 p3 = w2t[(9 + j) * 1024];
            const int ko = 4 * (s2 + 16 * j);
#pragma unroll
            for (int b = 0; b < 8; ++b) {
                const float4 h4 = *(const float4*)&lhh[b][ko];
                DOT4(u0[b], p0, h4);
                DOT4(u1[b], p1, h4);
                DOT4(u2[b], p2, h4);
                DOT4(u3[b], p3, h4);
            }
        }
        // reduce over 16 lanes: xor8 splits gate-pairs, xor4/2/1 scatter b; lane s2 -> b = s2&7
        const bool g8 = (s2 & 8) != 0;
        float U0[8], U1[8];
#pragma unroll
        for (int b = 0; b < 8; ++b) {
            U0[b] = (g8 ? u2[b] : u0[b]) + __shfl_xor(g8 ? u0[b] : u2[b], 8);
            U1[b] = (g8 ? u3[b] : u1[b]) + __shfl_xor(g8 ? u1[b] : u3[b], 8);
        }
        const bool e4 = (s2 & 4) != 0;
        float V0[4], V1[4];
#pragma unroll
        for (int i = 0; i < 4; ++i) {
            V0[i] = (e4 ? U0[i+4] : U0[i]) + __shfl_xor(e4 ? U0[i] : U0[i+4], 4);
            V1[i] = (e4 ? U1[i+4] : U1[i]) + __shfl_xor(e4 ? U1[i] : U1[i+4], 4);
        }
        const bool e2 = (s2 & 2) != 0;
        float X0[2], X1[2];
#pragma unroll
        for (int i = 0; i < 2; ++i) {
            X0[i] = (e2 ? V0[i+2] : V0[i]) + __shfl_xor(e2 ? V0[i] : V0[i+2], 2);
            X1[i] = (e2 ? V1[i+2] : V1[i]) + __shfl_xor(e2 ? V1[i] : V1[i+2], 2);
        }
        const bool e1 = (s2 & 1) != 0;
        const float D0 = (e1 ? X0[1] : X0[0]) + __shfl_xor(e1 ? X0[0] : X0[1], 1);
        const float D1 = (e1 ? X1[1] : X1[0]) + __shfl_xor(e1 ? X1[0] : X1[1], 1);
        const float E0 = __shfl_xor(D0, 8);   // other gate-pair from partner lane
        const float E1 = __shfl_xor(D1, 8);
        // lanes s2<8: i=D0, f=D1, g=E0, o=E1; lanes s2>=8: i=E0, f=E1, g=D0, o=D1 (b = s2&7)

        const float gi2 = lowh ? D0 : E0;
        const float gf2 = lowh ? D1 : E1;
        const float gg2 = lowh ? E0 : D0;
        const float go2 = lowh ? E1 : D1;
        const float i2 = sigm(gi2), f2g = sigm(gf2), g2v = tanhf_(gg2), o2 = sigm(go2);
        c2 = f2g * c2 + i2 * g2v;                 // both lane-halves keep identical c2
        const float h2n = o2 * tanhf_(c2);
        // fused FC, classes split: lower lanes 0..5, upper lanes 6..10
        const float* wfcp = Wfc + t * 64 + d2 + (lowh ? 0 : 6 * 8192);
        if (lowh) {
#pragma unroll
            for (int c = 0; c < 6; ++c) facc[c] += h2n * wfcp[c * 8192];
        } else {
#pragma unroll
            for (int c = 0; c < 5; ++c) facc[c] += h2n * wfcp[c * 8192];
        }
        __syncthreads();                 // C: all h1-new / h2-old reads done
        if (lowh) lhh[s2][128 + d2] = h2n;   // disjoint from next iter's h1 reads
    }

    // final FC reduction: sum facc over the 4 in-wave d2 groups (lane bits 4,5),
    // then across the 16 waves via LDS. Lower lanes carry c=0..5, upper c=6..10.
#pragma unroll
    for (int c = 0; c < 6; ++c) {
        facc[c] += __shfl_xor(facc[c], 16);
        facc[c] += __shfl_xor(facc[c], 32);
    }
    const int wv = tid >> 6;
    if ((tid & 63) < 16) {
        const int bb = tid & 7;
        if ((tid & 15) < 8) {
#pragma unroll
            for (int c = 0; c < 6; ++c) fpart[wv][bb][c] = facc[c];
        } else {
#pragma unroll
            for (int c = 0; c < 5; ++c) fpart[wv][bb][6 + c] = facc[c];
        }
    }
    __syncthreads();
    if (tid < BTILE * NCLS) {
        const int bb = tid / NCLS, c = tid - bb * NCLS;
        float v = bfc[c];
#pragma unroll
        for (int w = 0; w < 16; ++w) v += fpart[w][bb][c];
        out[(b0 + bb) * NCLS + c] = v;
    }
}

extern "C" void kernel_launch(void* const* d_in, const int* in_sizes, int n_in,
                              void* d_out, int out_size, void* d_ws, size_t ws_size,
                              hipStream_t stream) {
    const float* x    = (const float*)d_in[0];
    const float* Wih1 = (const float*)d_in[1];
    const float* Whh1 = (const float*)d_in[2];
    const float* Wih2 = (const float*)d_in[3];
    const float* Whh2 = (const float*)d_in[4];
    const float* Wfc  = (const float*)d_in[5];
    const float* bfc  = (const float*)d_in[6];
    float* out = (float*)d_out;
    float* ws  = (float*)d_ws;

    const int prep_elems = WT1F + WT2F;   // 114688 floats = 448 KB
    prep_weights<<<(prep_elems + 255) / 256, 256, 0, stream>>>(Whh1, Wih2, Whh2, ws);
    lstm_fused<<<256, 1024, 0, stream>>>(x, Wih1, Wfc, bfc, ws, out);
}

// Round 7
// 1940.805 us; speedup vs baseline: 1.8639x; 1.0800x over previous
//
#include <hip/hip_runtime.h>

// Problem constants
#define TSTEPS 128
#define NCLS 11
#define BTILE 8
// Re-packed weight workspace (floats), single [28 chunks][1024 lanes] float4 space:
//  chunks 0..15  (WT1): chunk = g*4+j, lane = d*8+s,  val = Whh1[g*128+d][4*(s+8j)+kk]
//  chunks 16..27 (WT2): chunk = 16+g*3+j, lane = d2*16+s, col = 4*(s+16j)+kk;
//                       col<128 -> Wih2[g*64+d2][col], else Whh2[g*64+d2][col-128]
#define WT1F 65536
#define WT2F 49152

__device__ __forceinline__ float sigm(float x) { return 1.0f / (1.0f + __expf(-x)); }
__device__ __forceinline__ float tanhf_(float x) { return 1.0f - 2.0f / (__expf(2.0f * x) + 1.0f); }

__global__ void prep_weights(const float* __restrict__ Whh1,
                             const float* __restrict__ Wih2,
                             const float* __restrict__ Whh2,
                             float* __restrict__ ws) {
    int idx = blockIdx.x * blockDim.x + threadIdx.x;
    if (idx < WT1F) {
        int kk = idx & 3, lane = (idx >> 2) & 1023, chunk = idx >> 12;
        int s = lane & 7, d = lane >> 3, g = chunk >> 2, j = chunk & 3;
        ws[idx] = Whh1[(g * 128 + d) * 128 + 4 * (s + 8 * j) + kk];
    } else if (idx < WT1F + WT2F) {
        int r = idx - WT1F;
        int kk = r & 3, lane = (r >> 2) & 1023, chunk = r >> 12;
        int s = lane & 15, d2 = lane >> 4, g = chunk / 3, j = chunk - 3 * g;
        int col = 4 * (s + 16 * j) + kk;
        int row = g * 64 + d2;
        ws[idx] = (col < 128) ? Wih2[row * 128 + col] : Whh2[row * 64 + (col - 128)];
    }
}

#define DOT4(acc, q, h) (acc += (q).x*(h).x + (q).y*(h).y + (q).z*(h).z + (q).w*(h).w)

// Persistent fused 2-layer LSTM + FC. grid=256 (1 block/CU), block=1024 (16 waves).
// HARD CONSTRAINT (rounds 1-5): this toolchain pins 1024-thread kernels at a
// 64-VGPR budget (launch_bounds / waves_per_eu both failed to raise it). The
// transient MAC set (32 accumulators + 16 weight regs + 4 h regs) is
// traffic-optimal and irreducible, so ALL persistent state beyond c1/c2 is
// evicted from registers:
//   - Wih1 input-projection weights: LDS table (round 5, kept).
//   - facc FC accumulators: LDS lfacc[1024][7] (pad 7 -> bank-stride 7,
//     gcd(7,32)=1 -> conflict-free), per-step read-modify-write.
//   - w2t pointer: folded into w1t (WT2 chunks live at +16*1024 float4s).
// L1 thread role: (d = tid>>3, s = tid&7): K-slice s; reduce-scatter -> lane s
//   owns batch b=s: every thread owns one (b,d) c1.
// L2 thread role: (d2 = tid>>4, s2 = tid&15), K=192 = h1|h2; both lane-halves
//   own (b=s2&7, d2) c2 (redundant compute); FC classes split 0..5 / 6..10.
__global__ __attribute__((amdgpu_flat_work_group_size(1024, 1024),
                          amdgpu_waves_per_eu(4, 4))) void lstm_fused(
    const float* __restrict__ x, const float* __restrict__ Wih1,
    const float* __restrict__ Wfc, const float* __restrict__ bfc,
    const float* __restrict__ ws, float* __restrict__ out) {

    const float4* __restrict__ w1 = (const float4*)ws;            // [28][1024]

    __shared__ __align__(16) float lx[BTILE][2 * TSTEPS + 4];  // x staged [b][c*128+t]
    __shared__ __align__(16) float lhh[BTILE][192];            // [b][0..127]=h1, [128..191]=h2
    __shared__ __align__(16) float4 lwih4[2][128];             // [0][d]=(ia,ib,fa,fb) [1][d]=(ga,gb,oa,ob)
    __shared__ float lfacc[1024][7];                           // per-thread FC accumulators (6 used)
    __shared__ float fpart[16][BTILE][NCLS];                   // per-wave FC partials (epilogue)

    const int tid = threadIdx.x;
    const int b0 = blockIdx.x * BTILE;

    for (int i = tid; i < BTILE * 2 * TSTEPS; i += 1024)
        lx[i >> 8][i & 255] = x[b0 * 256 + i];
    for (int i = tid; i < BTILE * 192; i += 1024)
        ((float*)lhh)[i] = 0.0f;
    for (int i = tid; i < 1024 * 7; i += 1024)
        ((float*)lfacc)[i] = 0.0f;
    if (tid < 128) {
        const float2* wp = (const float2*)Wih1;   // row r -> float2 at index r
        const float2 ri = wp[tid], rf = wp[128 + tid], rg = wp[256 + tid], ro = wp[384 + tid];
        lwih4[0][tid] = make_float4(ri.x, ri.y, rf.x, rf.y);
        lwih4[1][tid] = make_float4(rg.x, rg.y, ro.x, ro.y);
    }

    const int d  = tid >> 3;
    const int s  = tid & 7;
    const int d2 = tid >> 4;
    const int s2 = tid & 15;
    const bool lowh = (s2 < 8);

    const float4* __restrict__ w1t = w1 + tid;

    float c1 = 0.0f, c2 = 0.0f;

    __syncthreads();

#pragma unroll 1
    for (int t = 0; t < TSTEPS; ++t) {
        // ---------------- layer 1: partial gates over K-slice s ----------------
        float v0[8], v1[8], v2[8], v3[8];
#pragma unroll
        for (int b = 0; b < 8; ++b) { v0[b] = v1[b] = v2[b] = v3[b] = 0.0f; }
#pragma unroll
        for (int j = 0; j < 4; ++j) {
            const float4 q0 = w1t[(0  + j) * 1024];   // gate i
            const float4 q1 = w1t[(4  + j) * 1024];   // gate f
            const float4 q2 = w1t[(8  + j) * 1024];   // gate g
            const float4 q3 = w1t[(12 + j) * 1024];   // gate o
            const int ko = 4 * (s + 8 * j);
#pragma unroll
            for (int b = 0; b < 8; ++b) {
                const float4 h4 = *(const float4*)&lhh[b][ko];  // 8-way broadcast, conflict-free
                DOT4(v0[b], q0, h4);
                DOT4(v1[b], q1, h4);
                DOT4(v2[b], q2, h4);
                DOT4(v3[b], q3, h4);
            }
        }
        // reduce-scatter over the 8 s-lanes (static indices only): lane s -> b = s
        const bool f4 = (s & 4) != 0;
        float A0[4], A1[4], A2[4], A3[4];
#pragma unroll
        for (int i = 0; i < 4; ++i) {
            A0[i] = (f4 ? v0[i+4] : v0[i]) + __shfl_xor(f4 ? v0[i] : v0[i+4], 4);
            A1[i] = (f4 ? v1[i+4] : v1[i]) + __shfl_xor(f4 ? v1[i] : v1[i+4], 4);
            A2[i] = (f4 ? v2[i+4] : v2[i]) + __shfl_xor(f4 ? v2[i] : v2[i+4], 4);
            A3[i] = (f4 ? v3[i+4] : v3[i]) + __shfl_xor(f4 ? v3[i] : v3[i+4], 4);
        }
        const bool f2 = (s & 2) != 0;
        float B0[2], B1[2], B2[2], B3[2];
#pragma unroll
        for (int i = 0; i < 2; ++i) {
            B0[i] = (f2 ? A0[i+2] : A0[i]) + __shfl_xor(f2 ? A0[i] : A0[i+2], 2);
            B1[i] = (f2 ? A1[i+2] : A1[i]) + __shfl_xor(f2 ? A1[i] : A1[i+2], 2);
            B2[i] = (f2 ? A2[i+2] : A2[i]) + __shfl_xor(f2 ? A2[i] : A2[i+2], 2);
            B3[i] = (f2 ? A3[i+2] : A3[i]) + __shfl_xor(f2 ? A3[i] : A3[i+2], 2);
        }
        const bool f1 = (s & 1) != 0;
        const float r0 = (f1 ? B0[1] : B0[0]) + __shfl_xor(f1 ? B0[0] : B0[1], 1);
        const float r1 = (f1 ? B1[1] : B1[0]) + __shfl_xor(f1 ? B1[0] : B1[1], 1);
        const float r2 = (f1 ? B2[1] : B2[0]) + __shfl_xor(f1 ? B2[0] : B2[1], 1);
        const float r3 = (f1 ? B3[1] : B3[0]) + __shfl_xor(f1 ? B3[0] : B3[1], 1);

        // elementwise for (b = s, d) — all 1024 threads are owners.
        // Wih1 from LDS each step; opaque zero index defeats LICM hoisting.
        int zr; asm volatile("v_mov_b32 %0, 0" : "=v"(zr));
        const float4 wv0 = lwih4[0][d + zr];
        const float4 wv1 = lwih4[1][d + zr];
        const float x0 = lx[s][t], x1 = lx[s][TSTEPS + t];
        const float gi = r0 + wv0.x * x0 + wv0.y * x1;
        const float gf = r1 + wv0.z * x0 + wv0.w * x1;
        const float gg = r2 + wv1.x * x0 + wv1.y * x1;
        const float go = r3 + wv1.z * x0 + wv1.w * x1;
        const float i1 = sigm(gi), ff = sigm(gf), g1v = tanhf_(gg), o1 = sigm(go);
        c1 = ff * c1 + i1 * g1v;
        const float h1n = o1 * tanhf_(c1);

        __syncthreads();                 // A: all reads of old h1 done
        lhh[s][d] = h1n;
        __syncthreads();                 // B: new h1 visible

        // ---------------- layer 2: K = 192 (h1 new | h2 old), slice s2 ----------------
        float u0[8], u1[8], u2[8], u3[8];
#pragma unroll
        for (int b = 0; b < 8; ++b) { u0[b] = u1[b] = u2[b] = u3[b] = 0.0f; }
#pragma unroll
        for (int j = 0; j < 3; ++j) {
            const float4 p0 = w1t[(16 + j) * 1024];
            const float4 p1 = w1t[(19 + j) * 1024];
            const float4 p2 = w1t[(22 + j) * 1024];
            const float4 p3 = w1t[(25 + j) * 1024];
            const int ko = 4 * (s2 + 16 * j);
#pragma unroll
            for (int b = 0; b < 8; ++b) {
                const float4 h4 = *(const float4*)&lhh[b][ko];
                DOT4(u0[b], p0, h4);
                DOT4(u1[b], p1, h4);
                DOT4(u2[b], p2, h4);
                DOT4(u3[b], p3, h4);
            }
        }
        // reduce over 16 lanes: xor8 splits gate-pairs, xor4/2/1 scatter b; lane s2 -> b = s2&7
        const bool g8 = (s2 & 8) != 0;
        float U0[8], U1[8];
#pragma unroll
        for (int b = 0; b < 8; ++b) {
            U0[b] = (g8 ? u2[b] : u0[b]) + __shfl_xor(g8 ? u0[b] : u2[b], 8);
            U1[b] = (g8 ? u3[b] : u1[b]) + __shfl_xor(g8 ? u1[b] : u3[b], 8);
        }
        const bool e4 = (s2 & 4) != 0;
        float V0[4], V1[4];
#pragma unroll
        for (int i = 0; i < 4; ++i) {
            V0[i] = (e4 ? U0[i+4] : U0[i]) + __shfl_xor(e4 ? U0[i] : U0[i+4], 4);
            V1[i] = (e4 ? U1[i+4] : U1[i]) + __shfl_xor(e4 ? U1[i] : U1[i+4], 4);
        }
        const bool e2 = (s2 & 2) != 0;
        float X0[2], X1[2];
#pragma unroll
        for (int i = 0; i < 2; ++i) {
            X0[i] = (e2 ? V0[i+2] : V0[i]) + __shfl_xor(e2 ? V0[i] : V0[i+2], 2);
            X1[i] = (e2 ? V1[i+2] : V1[i]) + __shfl_xor(e2 ? V1[i] : V1[i+2], 2);
        }
        const bool e1 = (s2 & 1) != 0;
        const float D0 = (e1 ? X0[1] : X0[0]) + __shfl_xor(e1 ? X0[0] : X0[1], 1);
        const float D1 = (e1 ? X1[1] : X1[0]) + __shfl_xor(e1 ? X1[0] : X1[1], 1);
        const float E0 = __shfl_xor(D0, 8);   // other gate-pair from partner lane
        const float E1 = __shfl_xor(D1, 8);
        // lanes s2<8: i=D0, f=D1, g=E0, o=E1; lanes s2>=8: i=E0, f=E1, g=D0, o=D1 (b = s2&7)

        const float gi2 = lowh ? D0 : E0;
        const float gf2 = lowh ? D1 : E1;
        const float gg2 = lowh ? E0 : D0;
        const float go2 = lowh ? E1 : D1;
        const float i2 = sigm(gi2), f2g = sigm(gf2), g2v = tanhf_(gg2), o2 = sigm(go2);
        c2 = f2g * c2 + i2 * g2v;                 // both lane-halves keep identical c2
        const float h2n = o2 * tanhf_(c2);
        // fused FC into LDS accumulators, classes split: lower lanes 0..5, upper 6..10
        const float* wfcp = Wfc + t * 64 + d2 + (lowh ? 0 : 6 * 8192);
        if (lowh) {
#pragma unroll
            for (int c = 0; c < 6; ++c) lfacc[tid][c] += h2n * wfcp[c * 8192];
        } else {
#pragma unroll
            for (int c = 0; c < 5; ++c) lfacc[tid][c] += h2n * wfcp[c * 8192];
        }
        __syncthreads();                 // C: all h1-new / h2-old reads done
        if (lowh) lhh[s2][128 + d2] = h2n;   // disjoint from next iter's h1 reads
    }

    // final FC reduction: pull per-thread accumulators back to regs, sum over the
    // 4 in-wave d2 groups (lane bits 4,5), then across the 16 waves via LDS.
    float facc[6];
#pragma unroll
    for (int c = 0; c < 6; ++c) facc[c] = lfacc[tid][c];
#pragma unroll
    for (int c = 0; c < 6; ++c) {
        facc[c] += __shfl_xor(facc[c], 16);
        facc[c] += __shfl_xor(facc[c], 32);
    }
    const int wv = tid >> 6;
    if ((tid & 63) < 16) {
        const int bb = tid & 7;
        if ((tid & 15) < 8) {
#pragma unroll
            for (int c = 0; c < 6; ++c) fpart[wv][bb][c] = facc[c];
        } else {
#pragma unroll
            for (int c = 0; c < 5; ++c) fpart[wv][bb][6 + c] = facc[c];
        }
    }
    __syncthreads();
    if (tid < BTILE * NCLS) {
        const int bb = tid / NCLS, c = tid - bb * NCLS;
        float v = bfc[c];
#pragma unroll
        for (int w = 0; w < 16; ++w) v += fpart[w][bb][c];
        out[(b0 + bb) * NCLS + c] = v;
    }
}

extern "C" void kernel_launch(void* const* d_in, const int* in_sizes, int n_in,
                              void* d_out, int out_size, void* d_ws, size_t ws_size,
                              hipStream_t stream) {
    const float* x    = (const float*)d_in[0];
    const float* Wih1 = (const float*)d_in[1];
    const float* Whh1 = (const float*)d_in[2];
    const float* Wih2 = (const float*)d_in[3];
    const float* Whh2 = (const float*)d_in[4];
    const float* Wfc  = (const float*)d_in[5];
    const float* bfc  = (const float*)d_in[6];
    float* out = (float*)d_out;
    float* ws  = (float*)d_ws;

    const int prep_elems = WT1F + WT2F;   // 114688 floats = 448 KB
    prep_weights<<<(prep_elems + 255) / 256, 256, 0, stream>>>(Whh1, Wih2, Whh2, ws);
    lstm_fused<<<256, 1024, 0, stream>>>(x, Wih1, Wfc, bfc, ws, out);
}

// Round 8
// 1680.743 us; speedup vs baseline: 2.1523x; 1.1547x over previous
//
#include <hip/hip_runtime.h>

// Problem constants
#define TSTEPS 128
#define NCLS 11
#define BTILE 8
// ws layout (floats):
//  [0, WTOT): quad-interleaved weights: idx = (tid>>2)*448 + chunk*16 + (tid&3)*4 + kk
//    chunk 0..15  (L1): g = chunk>>2 (gate), j = chunk&3, s = tid&7, d = tid>>3,
//                       val = Whh1[(g*128+d)*128 + 4*(s+8j)+kk]
//    chunk 16..27 (L2): c2 = chunk-16, g = c2/3, j = c2%3, s = tid&15, d2 = tid>>4,
//                       col = 4*(s+16j)+kk; col<128 -> Wih2[g*64+d2][col] else Whh2[...][col-128]
//    => in-kernel: ONE base address/thread, all loads at immediate offset chunk*64B.
//  [WTOT, WTOT+WFCF): packed FC weights wsF[t][d2][16]:
//    slots 0..5 = Wfc[0..5][t*64+d2], slots 8..12 = Wfc[6..10][t*64+d2] (rest 0)
#define WTOT 114688
#define WFCF 131072

__device__ __forceinline__ float sigm(float x) { return 1.0f / (1.0f + __expf(-x)); }
__device__ __forceinline__ float tanhf_(float x) { return 1.0f - 2.0f / (__expf(2.0f * x) + 1.0f); }

__global__ void prep_weights(const float* __restrict__ Whh1,
                             const float* __restrict__ Wih2,
                             const float* __restrict__ Whh2,
                             const float* __restrict__ Wfc,
                             float* __restrict__ ws, int packFc) {
    int idx = blockIdx.x * blockDim.x + threadIdx.x;
    if (idx < WTOT) {
        int q = idx / 448;
        int r = idx % 448;
        int chunk = r >> 4;
        int lane = (r >> 2) & 3;
        int kk = idx & 3;
        int tid = q * 4 + lane;
        float v;
        if (chunk < 16) {
            int s = tid & 7, dd = tid >> 3, g = chunk >> 2, j = chunk & 3;
            v = Whh1[(g * 128 + dd) * 128 + 4 * (s + 8 * j) + kk];
        } else {
            int c2 = chunk - 16;
            int g = c2 / 3, j = c2 - 3 * g;
            int s = tid & 15, d2 = tid >> 4;
            int col = 4 * (s + 16 * j) + kk;
            int row = g * 64 + d2;
            v = (col < 128) ? Wih2[row * 128 + col] : Whh2[row * 64 + (col - 128)];
        }
        ws[idx] = v;
    } else if (packFc && idx < WTOT + WFCF) {
        int r = idx - WTOT;
        int t = r >> 10;
        int rem = r & 1023;
        int d2 = rem >> 4, slot = rem & 15;
        float v = 0.0f;
        if (slot < 6) v = Wfc[slot * 8192 + t * 64 + d2];
        else if (slot >= 8 && slot <= 12) v = Wfc[(slot - 2) * 8192 + t * 64 + d2];
        ws[idx] = v;
    }
}

#define DOT4(acc, q, h) (acc += (q).x*(h).x + (q).y*(h).y + (q).z*(h).z + (q).w*(h).w)

// Persistent fused 2-layer LSTM + FC. grid=256 (1 block/CU), block=1024 (16 waves).
// HARD CONSTRAINT (rounds 1-7): 1024-thread kernels get a 64-VGPR budget on this
// toolchain, immovable. Transient MAC set (32 acc + 16 weight + 4 h regs) is
// traffic-optimal; everything else lives in LDS or is addressed via a single
// base + immediate offsets:
//   - Wih1: LDS table (r5). FC accumulators: LDS lfacc[1024][7] (r7).
//   - weights: quad-interleaved layout -> 1 VGPR address pair, offset:chunk*64
//     (r8; kills the ~28 spilled/rebuilt 64-bit addresses = 1.95 GB/launch of
//     scratch re-reads seen in r7).
//   - Wfc: repacked [t][d2][16] -> dwordx4+dwordx2 from 1 base (r8).
__global__ __attribute__((amdgpu_flat_work_group_size(1024, 1024),
                          amdgpu_waves_per_eu(4, 4)))
void lstm_fused_t(const float* __restrict__ x, const float* __restrict__ Wih1,
                  const float* __restrict__ Wfc, const float* __restrict__ bfc,
                  const float* __restrict__ ws, float* __restrict__ out, int packed) {

    __shared__ __align__(16) float lx[BTILE][2 * TSTEPS + 4];  // x staged [b][c*128+t]
    __shared__ __align__(16) float lhh[BTILE][192];            // [b][0..127]=h1, [128..191]=h2
    __shared__ __align__(16) float4 lwih4[2][128];             // [0][d]=(ia,ib,fa,fb) [1][d]=(ga,gb,oa,ob)
    __shared__ float lfacc[1024][7];                           // per-thread FC accumulators (6 used)
    __shared__ float fpart[16][BTILE][NCLS];                   // per-wave FC partials (epilogue)

    const int tid = threadIdx.x;
    const int b0 = blockIdx.x * BTILE;

    for (int i = tid; i < BTILE * 2 * TSTEPS; i += 1024)
        lx[i >> 8][i & 255] = x[b0 * 256 + i];
    for (int i = tid; i < BTILE * 192; i += 1024)
        ((float*)lhh)[i] = 0.0f;
    for (int i = tid; i < 1024 * 7; i += 1024)
        ((float*)lfacc)[i] = 0.0f;
    if (tid < 128) {
        const float2* wp = (const float2*)Wih1;   // row r -> float2 at index r
        const float2 ri = wp[tid], rf = wp[128 + tid], rg = wp[256 + tid], ro = wp[384 + tid];
        lwih4[0][tid] = make_float4(ri.x, ri.y, rf.x, rf.y);
        lwih4[1][tid] = make_float4(rg.x, rg.y, ro.x, ro.y);
    }

    const int d  = tid >> 3;
    const int s  = tid & 7;
    const int d2 = tid >> 4;
    const int s2 = tid & 15;
    const bool lowh = (s2 < 8);

    // single weight base: all 28 chunk loads at immediate offset chunk*64 bytes
    const float4* __restrict__ wqt = (const float4*)ws + ((tid >> 2) * 112 + (tid & 3));
    const float* __restrict__ wfcPk = ws + WTOT + ((d2 << 4) + (lowh ? 0 : 8));

    float c1 = 0.0f, c2 = 0.0f;

    __syncthreads();

#pragma unroll 1
    for (int t = 0; t < TSTEPS; ++t) {
        // ---------------- layer 1: partial gates over K-slice s ----------------
        float v0[8], v1[8], v2[8], v3[8];
#pragma unroll
        for (int b = 0; b < 8; ++b) { v0[b] = v1[b] = v2[b] = v3[b] = 0.0f; }
#pragma unroll
        for (int j = 0; j < 4; ++j) {
            const float4 q0 = wqt[(0  + j) * 4];   // gate i
            const float4 q1 = wqt[(4  + j) * 4];   // gate f
            const float4 q2 = wqt[(8  + j) * 4];   // gate g
            const float4 q3 = wqt[(12 + j) * 4];   // gate o
            const int ko = 4 * (s + 8 * j);
#pragma unroll
            for (int b = 0; b < 8; ++b) {
                const float4 h4 = *(const float4*)&lhh[b][ko];  // 8-way broadcast, conflict-free
                DOT4(v0[b], q0, h4);
                DOT4(v1[b], q1, h4);
                DOT4(v2[b], q2, h4);
                DOT4(v3[b], q3, h4);
            }
        }
        // reduce-scatter over the 8 s-lanes (static indices only): lane s -> b = s
        const bool f4 = (s & 4) != 0;
        float A0[4], A1[4], A2[4], A3[4];
#pragma unroll
        for (int i = 0; i < 4; ++i) {
            A0[i] = (f4 ? v0[i+4] : v0[i]) + __shfl_xor(f4 ? v0[i] : v0[i+4], 4);
            A1[i] = (f4 ? v1[i+4] : v1[i]) + __shfl_xor(f4 ? v1[i] : v1[i+4], 4);
            A2[i] = (f4 ? v2[i+4] : v2[i]) + __shfl_xor(f4 ? v2[i] : v2[i+4], 4);
            A3[i] = (f4 ? v3[i+4] : v3[i]) + __shfl_xor(f4 ? v3[i] : v3[i+4], 4);
        }
        const bool f2 = (s & 2) != 0;
        float B0[2], B1[2], B2[2], B3[2];
#pragma unroll
        for (int i = 0; i < 2; ++i) {
            B0[i] = (f2 ? A0[i+2] : A0[i]) + __shfl_xor(f2 ? A0[i] : A0[i+2], 2);
            B1[i] = (f2 ? A1[i+2] : A1[i]) + __shfl_xor(f2 ? A1[i] : A1[i+2], 2);
            B2[i] = (f2 ? A2[i+2] : A2[i]) + __shfl_xor(f2 ? A2[i] : A2[i+2], 2);
            B3[i] = (f2 ? A3[i+2] : A3[i]) + __shfl_xor(f2 ? A3[i] : A3[i+2], 2);
        }
        const bool f1 = (s & 1) != 0;
        const float r0 = (f1 ? B0[1] : B0[0]) + __shfl_xor(f1 ? B0[0] : B0[1], 1);
        const float r1 = (f1 ? B1[1] : B1[0]) + __shfl_xor(f1 ? B1[0] : B1[1], 1);
        const float r2 = (f1 ? B2[1] : B2[0]) + __shfl_xor(f1 ? B2[0] : B2[1], 1);
        const float r3 = (f1 ? B3[1] : B3[0]) + __shfl_xor(f1 ? B3[0] : B3[1], 1);

        // elementwise for (b = s, d) — all 1024 threads are owners.
        // Wih1 from LDS each step; opaque zero index defeats LICM hoisting.
        int zr; asm volatile("v_mov_b32 %0, 0" : "=v"(zr));
        const float4 wv0 = lwih4[0][d + zr];
        const float4 wv1 = lwih4[1][d + zr];
        const float x0 = lx[s][t], x1 = lx[s][TSTEPS + t];
        const float gi = r0 + wv0.x * x0 + wv0.y * x1;
        const float gf = r1 + wv0.z * x0 + wv0.w * x1;
        const float gg = r2 + wv1.x * x0 + wv1.y * x1;
        const float go = r3 + wv1.z * x0 + wv1.w * x1;
        const float i1 = sigm(gi), ff = sigm(gf), g1v = tanhf_(gg), o1 = sigm(go);
        c1 = ff * c1 + i1 * g1v;
        const float h1n = o1 * tanhf_(c1);

        __syncthreads();                 // A: all reads of old h1 done
        lhh[s][d] = h1n;
        __syncthreads();                 // B: new h1 visible

        // ---------------- layer 2: K = 192 (h1 new | h2 old), slice s2 ----------------
        float u0[8], u1[8], u2[8], u3[8];
#pragma unroll
        for (int b = 0; b < 8; ++b) { u0[b] = u1[b] = u2[b] = u3[b] = 0.0f; }
#pragma unroll
        for (int j = 0; j < 3; ++j) {
            const float4 p0 = wqt[(16 + j) * 4];
            const float4 p1 = wqt[(19 + j) * 4];
            const float4 p2 = wqt[(22 + j) * 4];
            const float4 p3 = wqt[(25 + j) * 4];
            const int ko = 4 * (s2 + 16 * j);
#pragma unroll
            for (int b = 0; b < 8; ++b) {
                const float4 h4 = *(const float4*)&lhh[b][ko];
                DOT4(u0[b], p0, h4);
                DOT4(u1[b], p1, h4);
                DOT4(u2[b], p2, h4);
                DOT4(u3[b], p3, h4);
            }
        }
        // reduce over 16 lanes: xor8 splits gate-pairs, xor4/2/1 scatter b; lane s2 -> b = s2&7
        const bool g8 = (s2 & 8) != 0;
        float U0[8], U1[8];
#pragma unroll
        for (int b = 0; b < 8; ++b) {
            U0[b] = (g8 ? u2[b] : u0[b]) + __shfl_xor(g8 ? u0[b] : u2[b], 8);
            U1[b] = (g8 ? u3[b] : u1[b]) + __shfl_xor(g8 ? u1[b] : u3[b], 8);
        }
        const bool e4 = (s2 & 4) != 0;
        float V0[4], V1[4];
#pragma unroll
        for (int i = 0; i < 4; ++i) {
            V0[i] = (e4 ? U0[i+4] : U0[i]) + __shfl_xor(e4 ? U0[i] : U0[i+4], 4);
            V1[i] = (e4 ? U1[i+4] : U1[i]) + __shfl_xor(e4 ? U1[i] : U1[i+4], 4);
        }
        const bool e2 = (s2 & 2) != 0;
        float X0[2], X1[2];
#pragma unroll
        for (int i = 0; i < 2; ++i) {
            X0[i] = (e2 ? V0[i+2] : V0[i]) + __shfl_xor(e2 ? V0[i] : V0[i+2], 2);
            X1[i] = (e2 ? V1[i+2] : V1[i]) + __shfl_xor(e2 ? V1[i] : V1[i+2], 2);
        }
        const bool e1 = (s2 & 1) != 0;
        const float D0 = (e1 ? X0[1] : X0[0]) + __shfl_xor(e1 ? X0[0] : X0[1], 1);
        const float D1 = (e1 ? X1[1] : X1[0]) + __shfl_xor(e1 ? X1[0] : X1[1], 1);
        const float E0 = __shfl_xor(D0, 8);   // other gate-pair from partner lane
        const float E1 = __shfl_xor(D1, 8);
        // lanes s2<8: i=D0, f=D1, g=E0, o=E1; lanes s2>=8: i=E0, f=E1, g=D0, o=D1 (b = s2&7)

        const float gi2 = lowh ? D0 : E0;
        const float gf2 = lowh ? D1 : E1;
        const float gg2 = lowh ? E0 : D0;
        const float go2 = lowh ? E1 : D1;
        const float i2 = sigm(gi2), f2g = sigm(gf2), g2v = tanhf_(gg2), o2 = sigm(go2);
        c2 = f2g * c2 + i2 * g2v;                 // both lane-halves keep identical c2
        const float h2n = o2 * tanhf_(c2);
        // fused FC into LDS accumulators, classes split: lower lanes 0..5, upper 6..10
        if (packed) {
            const float* fp = wfcPk + (t << 10);
            const float4 fa = *(const float4*)fp;
            const float2 fb = *(const float2*)(fp + 4);
            lfacc[tid][0] += h2n * fa.x;
            lfacc[tid][1] += h2n * fa.y;
            lfacc[tid][2] += h2n * fa.z;
            lfacc[tid][3] += h2n * fa.w;
            lfacc[tid][4] += h2n * fb.x;
            if (lowh) lfacc[tid][5] += h2n * fb.y;
        } else {
            const float* wfcp = Wfc + t * 64 + d2 + (lowh ? 0 : 6 * 8192);
            if (lowh) {
#pragma unroll
                for (int c = 0; c < 6; ++c) lfacc[tid][c] += h2n * wfcp[c * 8192];
            } else {
#pragma unroll
                for (int c = 0; c < 5; ++c) lfacc[tid][c] += h2n * wfcp[c * 8192];
            }
        }
        __syncthreads();                 // C: all h1-new / h2-old reads done
        if (lowh) lhh[s2][128 + d2] = h2n;   // disjoint from next iter's h1 reads
    }

    // final FC reduction: pull per-thread accumulators back to regs, sum over the
    // 4 in-wave d2 groups (lane bits 4,5), then across the 16 waves via LDS.
    float facc[6];
#pragma unroll
    for (int c = 0; c < 6; ++c) facc[c] = lfacc[tid][c];
#pragma unroll
    for (int c = 0; c < 6; ++c) {
        facc[c] += __shfl_xor(facc[c], 16);
        facc[c] += __shfl_xor(facc[c], 32);
    }
    const int wv = tid >> 6;
    if ((tid & 63) < 16) {
        const int bb = tid & 7;
        if ((tid & 15) < 8) {
#pragma unroll
            for (int c = 0; c < 6; ++c) fpart[wv][bb][c] = facc[c];
        } else {
#pragma unroll
            for (int c = 0; c < 5; ++c) fpart[wv][bb][6 + c] = facc[c];
        }
    }
    __syncthreads();
    if (tid < BTILE * NCLS) {
        const int bb = tid / NCLS, c = tid - bb * NCLS;
        float v = bfc[c];
#pragma unroll
        for (int w = 0; w < 16; ++w) v += fpart[w][bb][c];
        out[(b0 + bb) * NCLS + c] = v;
    }
}

extern "C" void kernel_launch(void* const* d_in, const int* in_sizes, int n_in,
                              void* d_out, int out_size, void* d_ws, size_t ws_size,
                              hipStream_t stream) {
    const float* x    = (const float*)d_in[0];
    const float* Wih1 = (const float*)d_in[1];
    const float* Whh1 = (const float*)d_in[2];
    const float* Wih2 = (const float*)d_in[3];
    const float* Whh2 = (const float*)d_in[4];
    const float* Wfc  = (const float*)d_in[5];
    const float* bfc  = (const float*)d_in[6];
    float* out = (float*)d_out;
    float* ws  = (float*)d_ws;

    const int packed = (ws_size >= (size_t)(WTOT + WFCF) * 4) ? 1 : 0;
    const int prep_elems = WTOT + (packed ? WFCF : 0);   // 448 KB (+512 KB packed FC)
    prep_weights<<<(prep_elems + 255) / 256, 256, 0, stream>>>(Whh1, Wih2, Whh2, Wfc, ws, packed);
    lstm_fused_t<<<256, 1024, 0, stream>>>(x, Wih1, Wfc, bfc, ws, out, packed);
}

// Round 9
// 1373.877 us; speedup vs baseline: 2.6330x; 1.2234x over previous
//
#include <hip/hip_runtime.h>

// Problem constants
#define TSTEPS 128
#define NCLS 11
#define BTILE 8
// ws layout (floats):
//  [0, WTOT): quad-interleaved weights: idx = (tid>>2)*448 + chunk*16 + (tid&3)*4 + kk
//    chunk 0..15  (L1): g = chunk>>2 (gate), j = chunk&3, s = tid&7, d = tid>>3,
//                       val = Whh1[(g*128+d)*128 + 4*(s+8j)+kk]
//    chunk 16..27 (L2): c2 = chunk-16, g = c2/3, j = c2%3, s = tid&15, d2 = tid>>4,
//                       col = 4*(s+16j)+kk; col<128 -> Wih2[g*64+d2][col] else Whh2[...][col-128]
//    => in-kernel: ONE base address/thread, all loads at immediate offset chunk*64B.
//  [WTOT, WTOT+WFCF): packed FC weights wsF[t][d2][16]:
//    slots 0..5 = Wfc[0..5][t*64+d2], slots 8..12 = Wfc[6..10][t*64+d2] (rest 0)
#define WTOT 114688
#define WFCF 131072

__device__ __forceinline__ float sigm(float x) { return 1.0f / (1.0f + __expf(-x)); }
__device__ __forceinline__ float tanhf_(float x) { return 1.0f - 2.0f / (__expf(2.0f * x) + 1.0f); }

__global__ void prep_weights(const float* __restrict__ Whh1,
                             const float* __restrict__ Wih2,
                             const float* __restrict__ Whh2,
                             const float* __restrict__ Wfc,
                             float* __restrict__ ws, int packFc) {
    int idx = blockIdx.x * blockDim.x + threadIdx.x;
    if (idx < WTOT) {
        int q = idx / 448;
        int r = idx % 448;
        int chunk = r >> 4;
        int lane = (r >> 2) & 3;
        int kk = idx & 3;
        int tid = q * 4 + lane;
        float v;
        if (chunk < 16) {
            int s = tid & 7, dd = tid >> 3, g = chunk >> 2, j = chunk & 3;
            v = Whh1[(g * 128 + dd) * 128 + 4 * (s + 8 * j) + kk];
        } else {
            int c2 = chunk - 16;
            int g = c2 / 3, j = c2 - 3 * g;
            int s = tid & 15, d2 = tid >> 4;
            int col = 4 * (s + 16 * j) + kk;
            int row = g * 64 + d2;
            v = (col < 128) ? Wih2[row * 128 + col] : Whh2[row * 64 + (col - 128)];
        }
        ws[idx] = v;
    } else if (packFc && idx < WTOT + WFCF) {
        int r = idx - WTOT;
        int t = r >> 10;
        int rem = r & 1023;
        int d2 = rem >> 4, slot = rem & 15;
        float v = 0.0f;
        if (slot < 6) v = Wfc[slot * 8192 + t * 64 + d2];
        else if (slot >= 8 && slot <= 12) v = Wfc[(slot - 2) * 8192 + t * 64 + d2];
        ws[idx] = v;
    }
}

#define DOT4(acc, q, h) (acc += (q).x*(h).x + (q).y*(h).y + (q).z*(h).z + (q).w*(h).w)

// Persistent fused 2-layer LSTM + FC. grid=256 (1 block/CU), block=1024 (16 waves).
// HARD CONSTRAINT (rounds 1-8): 1024-thread kernels get a 64-VGPR budget on this
// toolchain, immovable. r8 showed the full 4-gate MAC set (32 acc + 16 weight +
// 4 h = 52 transient + 14 persistent) still spills ~10 regs (1.5 GB scratch
// round-trip). r9 = GATE-PAIR SPLIT: each layer's MACs run as two passes
// (gates i,f then g,o): 16 acc + 8 weight + 4 h = 28 transient. Shuffle and
// weight-load counts unchanged; h-tile LDS reads double (DS pipe has headroom).
// sched_barrier(0) between passes stops the scheduler re-fusing them.
// Other r5-r8 measures kept: Wih1 in LDS, FC accums in LDS lfacc, single weight
// base + immediate offsets, packed Wfc [t][d2][16].
__global__ __attribute__((amdgpu_flat_work_group_size(1024, 1024),
                          amdgpu_waves_per_eu(4, 4)))
void lstm_fused_t(const float* __restrict__ x, const float* __restrict__ Wih1,
                  const float* __restrict__ Wfc, const float* __restrict__ bfc,
                  const float* __restrict__ ws, float* __restrict__ out, int packed) {

    __shared__ __align__(16) float lx[BTILE][2 * TSTEPS + 4];  // x staged [b][c*128+t]
    __shared__ __align__(16) float lhh[BTILE][192];            // [b][0..127]=h1, [128..191]=h2
    __shared__ __align__(16) float4 lwih4[2][128];             // [0][d]=(ia,ib,fa,fb) [1][d]=(ga,gb,oa,ob)
    __shared__ float lfacc[1024][7];                           // per-thread FC accumulators (6 used)
    __shared__ float fpart[16][BTILE][NCLS];                   // per-wave FC partials (epilogue)

    const int tid = threadIdx.x;
    const int b0 = blockIdx.x * BTILE;

    for (int i = tid; i < BTILE * 2 * TSTEPS; i += 1024)
        lx[i >> 8][i & 255] = x[b0 * 256 + i];
    for (int i = tid; i < BTILE * 192; i += 1024)
        ((float*)lhh)[i] = 0.0f;
    for (int i = tid; i < 1024 * 7; i += 1024)
        ((float*)lfacc)[i] = 0.0f;
    if (tid < 128) {
        const float2* wp = (const float2*)Wih1;   // row r -> float2 at index r
        const float2 ri = wp[tid], rf = wp[128 + tid], rg = wp[256 + tid], ro = wp[384 + tid];
        lwih4[0][tid] = make_float4(ri.x, ri.y, rf.x, rf.y);
        lwih4[1][tid] = make_float4(rg.x, rg.y, ro.x, ro.y);
    }

    const int d  = tid >> 3;
    const int s  = tid & 7;
    const int d2 = tid >> 4;
    const int s2 = tid & 15;
    const bool lowh = (s2 < 8);

    // single weight base: all 28 chunk loads at immediate offset chunk*64 bytes
    const float4* __restrict__ wqt = (const float4*)ws + ((tid >> 2) * 112 + (tid & 3));
    const float* __restrict__ wfcPk = ws + WTOT + ((d2 << 4) + (lowh ? 0 : 8));

    float c1 = 0.0f, c2 = 0.0f;

    __syncthreads();

#pragma unroll 1
    for (int t = 0; t < TSTEPS; ++t) {
        const bool f4 = (s & 4) != 0;
        const bool f2 = (s & 2) != 0;
        const bool f1 = (s & 1) != 0;

        // ======== layer 1, pass A: gates i,f over K-slice s (16 accumulators) ========
        float ri, rf_;
        {
            float va[8], vb[8];
#pragma unroll
            for (int b = 0; b < 8; ++b) { va[b] = vb[b] = 0.0f; }
#pragma unroll
            for (int j = 0; j < 4; ++j) {
                const float4 qa = wqt[(0 + j) * 4];   // gate i
                const float4 qb = wqt[(4 + j) * 4];   // gate f
                const int ko = 4 * (s + 8 * j);
#pragma unroll
                for (int b = 0; b < 8; ++b) {
                    const float4 h4 = *(const float4*)&lhh[b][ko];  // broadcast, conflict-free
                    DOT4(va[b], qa, h4);
                    DOT4(vb[b], qb, h4);
                }
            }
            float Aa[4], Ab[4];
#pragma unroll
            for (int i = 0; i < 4; ++i) {
                Aa[i] = (f4 ? va[i+4] : va[i]) + __shfl_xor(f4 ? va[i] : va[i+4], 4);
                Ab[i] = (f4 ? vb[i+4] : vb[i]) + __shfl_xor(f4 ? vb[i] : vb[i+4], 4);
            }
            float Ba[2], Bb[2];
#pragma unroll
            for (int i = 0; i < 2; ++i) {
                Ba[i] = (f2 ? Aa[i+2] : Aa[i]) + __shfl_xor(f2 ? Aa[i] : Aa[i+2], 2);
                Bb[i] = (f2 ? Ab[i+2] : Ab[i]) + __shfl_xor(f2 ? Ab[i] : Ab[i+2], 2);
            }
            ri  = (f1 ? Ba[1] : Ba[0]) + __shfl_xor(f1 ? Ba[0] : Ba[1], 1);
            rf_ = (f1 ? Bb[1] : Bb[0]) + __shfl_xor(f1 ? Bb[0] : Bb[1], 1);
        }
        __builtin_amdgcn_sched_barrier(0);   // keep pass B's loads out of pass A

        // ======== layer 1, pass B: gates g,o ========
        float rg, ro;
        {
            float va[8], vb[8];
#pragma unroll
            for (int b = 0; b < 8; ++b) { va[b] = vb[b] = 0.0f; }
#pragma unroll
            for (int j = 0; j < 4; ++j) {
                const float4 qa = wqt[(8  + j) * 4];  // gate g
                const float4 qb = wqt[(12 + j) * 4];  // gate o
                const int ko = 4 * (s + 8 * j);
#pragma unroll
                for (int b = 0; b < 8; ++b) {
                    const float4 h4 = *(const float4*)&lhh[b][ko];
                    DOT4(va[b], qa, h4);
                    DOT4(vb[b], qb, h4);
                }
            }
            float Aa[4], Ab[4];
#pragma unroll
            for (int i = 0; i < 4; ++i) {
                Aa[i] = (f4 ? va[i+4] : va[i]) + __shfl_xor(f4 ? va[i] : va[i+4], 4);
                Ab[i] = (f4 ? vb[i+4] : vb[i]) + __shfl_xor(f4 ? vb[i] : vb[i+4], 4);
            }
            float Ba[2], Bb[2];
#pragma unroll
            for (int i = 0; i < 2; ++i) {
                Ba[i] = (f2 ? Aa[i+2] : Aa[i]) + __shfl_xor(f2 ? Aa[i] : Aa[i+2], 2);
                Bb[i] = (f2 ? Ab[i+2] : Ab[i]) + __shfl_xor(f2 ? Ab[i] : Ab[i+2], 2);
            }
            rg = (f1 ? Ba[1] : Ba[0]) + __shfl_xor(f1 ? Ba[0] : Ba[1], 1);
            ro = (f1 ? Bb[1] : Bb[0]) + __shfl_xor(f1 ? Bb[0] : Bb[1], 1);
        }
        __builtin_amdgcn_sched_barrier(0);

        // elementwise for (b = s, d) — all 1024 threads are owners.
        // Wih1 from LDS each step; opaque zero index defeats LICM hoisting.
        int zr; asm volatile("v_mov_b32 %0, 0" : "=v"(zr));
        const float4 wv0 = lwih4[0][d + zr];
        const float4 wv1 = lwih4[1][d + zr];
        const float x0 = lx[s][t], x1 = lx[s][TSTEPS + t];
        const float gi = ri  + wv0.x * x0 + wv0.y * x1;
        const float gf = rf_ + wv0.z * x0 + wv0.w * x1;
        const float gg = rg  + wv1.x * x0 + wv1.y * x1;
        const float go = ro  + wv1.z * x0 + wv1.w * x1;
        const float i1 = sigm(gi), ff = sigm(gf), g1v = tanhf_(gg), o1 = sigm(go);
        c1 = ff * c1 + i1 * g1v;
        const float h1n = o1 * tanhf_(c1);

        __syncthreads();                 // A: all reads of old h1 done
        lhh[s][d] = h1n;
        __syncthreads();                 // B: new h1 visible

        const bool g8 = (s2 & 8) != 0;
        const bool e4 = (s2 & 4) != 0;
        const bool e2 = (s2 & 2) != 0;
        const bool e1 = (s2 & 1) != 0;

        // ======== layer 2, pass A: gates i,f over K=192 slice s2 ========
        float DA, EA;
        {
            float ua[8], ub[8];
#pragma unroll
            for (int b = 0; b < 8; ++b) { ua[b] = ub[b] = 0.0f; }
#pragma unroll
            for (int j = 0; j < 3; ++j) {
                const float4 pa = wqt[(16 + j) * 4];  // gate i
                const float4 pb = wqt[(19 + j) * 4];  // gate f
                const int ko = 4 * (s2 + 16 * j);
#pragma unroll
                for (int b = 0; b < 8; ++b) {
                    const float4 h4 = *(const float4*)&lhh[b][ko];
                    DOT4(ua[b], pa, h4);
                    DOT4(ub[b], pb, h4);
                }
            }
            float T[8];
#pragma unroll
            for (int b = 0; b < 8; ++b)
                T[b] = (g8 ? ub[b] : ua[b]) + __shfl_xor(g8 ? ua[b] : ub[b], 8);
            float V[4];
#pragma unroll
            for (int i = 0; i < 4; ++i)
                V[i] = (e4 ? T[i+4] : T[i]) + __shfl_xor(e4 ? T[i] : T[i+4], 4);
            float X[2];
#pragma unroll
            for (int i = 0; i < 2; ++i)
                X[i] = (e2 ? V[i+2] : V[i]) + __shfl_xor(e2 ? V[i] : V[i+2], 2);
            DA = (e1 ? X[1] : X[0]) + __shfl_xor(e1 ? X[0] : X[1], 1);
            EA = __shfl_xor(DA, 8);
        }
        __builtin_amdgcn_sched_barrier(0);

        // ======== layer 2, pass B: gates g,o ========
        float DB, EB;
        {
            float ua[8], ub[8];
#pragma unroll
            for (int b = 0; b < 8; ++b) { ua[b] = ub[b] = 0.0f; }
#pragma unroll
            for (int j = 0; j < 3; ++j) {
                const float4 pa = wqt[(22 + j) * 4];  // gate g
                const float4 pb = wqt[(25 + j) * 4];  // gate o
                const int ko = 4 * (s2 + 16 * j);
#pragma unroll
                for (int b = 0; b < 8; ++b) {
                    const float4 h4 = *(const float4*)&lhh[b][ko];
                    DOT4(ua[b], pa, h4);
                    DOT4(ub[b], pb, h4);
                }
            }
            float T[8];
#pragma unroll
            for (int b = 0; b < 8; ++b)
                T[b] = (g8 ? ub[b] : ua[b]) + __shfl_xor(g8 ? ua[b] : ub[b], 8);
            float V[4];
#pragma unroll
            for (int i = 0; i < 4; ++i)
                V[i] = (e4 ? T[i+4] : T[i]) + __shfl_xor(e4 ? T[i] : T[i+4], 4);
            float X[2];
#pragma unroll
            for (int i = 0; i < 2; ++i)
                X[i] = (e2 ? V[i+2] : V[i]) + __shfl_xor(e2 ? V[i] : V[i+2], 2);
            DB = (e1 ? X[1] : X[0]) + __shfl_xor(e1 ? X[0] : X[1], 1);
            EB = __shfl_xor(DB, 8);
        }
        // lanes s2<8: i=DA, f=EA, g=DB, o=EB; lanes s2>=8: i=EA, f=DA, g=EB, o=DB (b = s2&7)

        const float gi2 = lowh ? DA : EA;
        const float gf2 = lowh ? EA : DA;
        const float gg2 = lowh ? DB : EB;
        const float go2 = lowh ? EB : DB;
        const float i2 = sigm(gi2), f2g = sigm(gf2), g2v = tanhf_(gg2), o2 = sigm(go2);
        c2 = f2g * c2 + i2 * g2v;                 // both lane-halves keep identical c2
        const float h2n = o2 * tanhf_(c2);
        // fused FC into LDS accumulators, classes split: lower lanes 0..5, upper 6..10
        if (packed) {
            const float* fp = wfcPk + (t << 10);
            const float4 fa = *(const float4*)fp;
            const float2 fb = *(const float2*)(fp + 4);
            lfacc[tid][0] += h2n * fa.x;
            lfacc[tid][1] += h2n * fa.y;
            lfacc[tid][2] += h2n * fa.z;
            lfacc[tid][3] += h2n * fa.w;
            lfacc[tid][4] += h2n * fb.x;
            if (lowh) lfacc[tid][5] += h2n * fb.y;
        } else {
            const float* wfcp = Wfc + t * 64 + d2 + (lowh ? 0 : 6 * 8192);
            if (lowh) {
#pragma unroll
                for (int c = 0; c < 6; ++c) lfacc[tid][c] += h2n * wfcp[c * 8192];
            } else {
#pragma unroll
                for (int c = 0; c < 5; ++c) lfacc[tid][c] += h2n * wfcp[c * 8192];
            }
        }
        __syncthreads();                 // C: all h1-new / h2-old reads done
        if (lowh) lhh[s2][128 + d2] = h2n;   // disjoint from next iter's h1 reads
    }

    // final FC reduction: pull per-thread accumulators back to regs, sum over the
    // 4 in-wave d2 groups (lane bits 4,5), then across the 16 waves via LDS.
    float facc[6];
#pragma unroll
    for (int c = 0; c < 6; ++c) facc[c] = lfacc[tid][c];
#pragma unroll
    for (int c = 0; c < 6; ++c) {
        facc[c] += __shfl_xor(facc[c], 16);
        facc[c] += __shfl_xor(facc[c], 32);
    }
    const int wv = tid >> 6;
    if ((tid & 63) < 16) {
        const int bb = tid & 7;
        if ((tid & 15) < 8) {
#pragma unroll
            for (int c = 0; c < 6; ++c) fpart[wv][bb][c] = facc[c];
        } else {
#pragma unroll
            for (int c = 0; c < 5; ++c) fpart[wv][bb][6 + c] = facc[c];
        }
    }
    __syncthreads();
    if (tid < BTILE * NCLS) {
        const int bb = tid / NCLS, c = tid - bb * NCLS;
        float v = bfc[c];
#pragma unroll
        for (int w = 0; w < 16; ++w) v += fpart[w][bb][c];
        out[(b0 + bb) * NCLS + c] = v;
    }
}

extern "C" void kernel_launch(void* const* d_in, const int* in_sizes, int n_in,
                              void* d_out, int out_size, void* d_ws, size_t ws_size,
                              hipStream_t stream) {
    const float* x    = (const float*)d_in[0];
    const float* Wih1 = (const float*)d_in[1];
    const float* Whh1 = (const float*)d_in[2];
    const float* Wih2 = (const float*)d_in[3];
    const float* Whh2 = (const float*)d_in[4];
    const float* Wfc  = (const float*)d_in[5];
    const float* bfc  = (const float*)d_in[6];
    float* out = (float*)d_out;
    float* ws  = (float*)d_ws;

    const int packed = (ws_size >= (size_t)(WTOT + WFCF) * 4) ? 1 : 0;
    const int prep_elems = WTOT + (packed ? WFCF : 0);   // 448 KB (+512 KB packed FC)
    prep_weights<<<(prep_elems + 255) / 256, 256, 0, stream>>>(Whh1, Wih2, Whh2, Wfc, ws, packed);
    lstm_fused_t<<<256, 1024, 0, stream>>>(x, Wih1, Wfc, bfc, ws, out, packed);
}

// Round 10
// 1352.621 us; speedup vs baseline: 2.6744x; 1.0157x over previous
//
#include <hip/hip_runtime.h>

// Problem constants
#define TSTEPS 128
#define NCLS 11
#define BTILE 8
// ws layout (floats):
//  [0, WTOT): quad-interleaved weights: idx = (tid>>2)*448 + chunk*16 + (tid&3)*4 + kk
//    chunk 0..15  (L1): g = chunk>>2 (gate), j = chunk&3, s = tid&7, d = tid>>3,
//                       val = Whh1[(g*128+d)*128 + 4*(s+8j)+kk]
//    chunk 16..27 (L2): c2 = chunk-16, g = c2/3, j = c2%3, s = tid&15, d2 = tid>>4,
//                       col = 4*(s+16j)+kk; col<128 -> Wih2[g*64+d2][col] else Whh2[...][col-128]
//    => in-kernel: ONE base address/thread, all loads at immediate offset chunk*64B.
//  [WTOT, WTOT+WFCF): packed FC weights wsF[t][d2][16]:
//    slots 0..5 = Wfc[0..5][t*64+d2], slots 8..12 = Wfc[6..10][t*64+d2] (rest 0)
#define WTOT 114688
#define WFCF 131072

__device__ __forceinline__ float sigm(float x) { return 1.0f / (1.0f + __expf(-x)); }
__device__ __forceinline__ float tanhf_(float x) { return 1.0f - 2.0f / (__expf(2.0f * x) + 1.0f); }

// DPP lane exchange on VALU (no DS pipe, no LDS round-trip latency).
// ctrl: 0xB1 = quad_perm[1,0,3,2] (xor1), 0x4E = quad_perm[2,3,0,1] (xor2),
//       0x141 = row_half_mirror (p <-> 7-p within each 8; flips lane bit2),
//       0x128 = row_ror:8 (c <-> c^8 within each 16).
template <int CTRL>
__device__ __forceinline__ float dppf(float x) {
    return __int_as_float(__builtin_amdgcn_update_dpp(
        0, __float_as_int(x), CTRL, 0xF, 0xF, true));
}

__global__ void prep_weights(const float* __restrict__ Whh1,
                             const float* __restrict__ Wih2,
                             const float* __restrict__ Whh2,
                             const float* __restrict__ Wfc,
                             float* __restrict__ ws, int packFc) {
    int idx = blockIdx.x * blockDim.x + threadIdx.x;
    if (idx < WTOT) {
        int q = idx / 448;
        int r = idx % 448;
        int chunk = r >> 4;
        int lane = (r >> 2) & 3;
        int kk = idx & 3;
        int tid = q * 4 + lane;
        float v;
        if (chunk < 16) {
            int s = tid & 7, dd = tid >> 3, g = chunk >> 2, j = chunk & 3;
            v = Whh1[(g * 128 + dd) * 128 + 4 * (s + 8 * j) + kk];
        } else {
            int c2 = chunk - 16;
            int g = c2 / 3, j = c2 - 3 * g;
            int s = tid & 15, d2 = tid >> 4;
            int col = 4 * (s + 16 * j) + kk;
            int row = g * 64 + d2;
            v = (col < 128) ? Wih2[row * 128 + col] : Whh2[row * 64 + (col - 128)];
        }
        ws[idx] = v;
    } else if (packFc && idx < WTOT + WFCF) {
        int r = idx - WTOT;
        int t = r >> 10;
        int rem = r & 1023;
        int d2 = rem >> 4, slot = rem & 15;
        float v = 0.0f;
        if (slot < 6) v = Wfc[slot * 8192 + t * 64 + d2];
        else if (slot >= 8 && slot <= 12) v = Wfc[(slot - 2) * 8192 + t * 64 + d2];
        ws[idx] = v;
    }
}

#define DOT4(acc, q, h) (acc += (q).x*(h).x + (q).y*(h).y + (q).z*(h).z + (q).w*(h).w)

// Persistent fused 2-layer LSTM + FC. grid=256 (1 block/CU), block=1024 (16 waves).
// r1-r8: engineered to the immovable 64-VGPR budget (gate-pair split MACs,
// Wih1+FC accums in LDS, single weight base + immediate offsets). r9 result:
// scratch spills = 0 (FETCH 5 MB = inputs), VALUBusy ~99.
// r10: all in-loop __shfl_xor -> DPP (cndmask + v_mov_dpp + add). The butterfly
// stages were DS-pipe round trips (~40 cyc lgkmcnt latency each, 7 dependent
// stages/step); DPP runs on VALU with forwarding latency and frees DS slots.
// xor4-boundary stage uses row_half_mirror (any bit2-flipping involution routes
// the reduce-scatter identically; final owner lane p still gets b=p).
__global__ __attribute__((amdgpu_flat_work_group_size(1024, 1024),
                          amdgpu_waves_per_eu(4, 4)))
void lstm_fused_t(const float* __restrict__ x, const float* __restrict__ Wih1,
                  const float* __restrict__ Wfc, const float* __restrict__ bfc,
                  const float* __restrict__ ws, float* __restrict__ out, int packed) {

    __shared__ __align__(16) float lx[BTILE][2 * TSTEPS + 4];  // x staged [b][c*128+t]
    __shared__ __align__(16) float lhh[BTILE][192];            // [b][0..127]=h1, [128..191]=h2
    __shared__ __align__(16) float4 lwih4[2][128];             // [0][d]=(ia,ib,fa,fb) [1][d]=(ga,gb,oa,ob)
    __shared__ float lfacc[1024][7];                           // per-thread FC accumulators (6 used)
    __shared__ float fpart[16][BTILE][NCLS];                   // per-wave FC partials (epilogue)

    const int tid = threadIdx.x;
    const int b0 = blockIdx.x * BTILE;

    for (int i = tid; i < BTILE * 2 * TSTEPS; i += 1024)
        lx[i >> 8][i & 255] = x[b0 * 256 + i];
    for (int i = tid; i < BTILE * 192; i += 1024)
        ((float*)lhh)[i] = 0.0f;
    for (int i = tid; i < 1024 * 7; i += 1024)
        ((float*)lfacc)[i] = 0.0f;
    if (tid < 128) {
        const float2* wp = (const float2*)Wih1;   // row r -> float2 at index r
        const float2 ri = wp[tid], rf = wp[128 + tid], rg = wp[256 + tid], ro = wp[384 + tid];
        lwih4[0][tid] = make_float4(ri.x, ri.y, rf.x, rf.y);
        lwih4[1][tid] = make_float4(rg.x, rg.y, ro.x, ro.y);
    }

    const int d  = tid >> 3;
    const int s  = tid & 7;
    const int d2 = tid >> 4;
    const int s2 = tid & 15;
    const bool lowh = (s2 < 8);

    // single weight base: all 28 chunk loads at immediate offset chunk*64 bytes
    const float4* __restrict__ wqt = (const float4*)ws + ((tid >> 2) * 112 + (tid & 3));
    const float* __restrict__ wfcPk = ws + WTOT + ((d2 << 4) + (lowh ? 0 : 8));

    float c1 = 0.0f, c2 = 0.0f;

    __syncthreads();

#pragma unroll 1
    for (int t = 0; t < TSTEPS; ++t) {
        const bool f4 = (s & 4) != 0;
        const bool f2 = (s & 2) != 0;
        const bool f1 = (s & 1) != 0;

        // ======== layer 1, pass A: gates i,f over K-slice s (16 accumulators) ========
        float ri, rf_;
        {
            float va[8], vb[8];
#pragma unroll
            for (int b = 0; b < 8; ++b) { va[b] = vb[b] = 0.0f; }
#pragma unroll
            for (int j = 0; j < 4; ++j) {
                const float4 qa = wqt[(0 + j) * 4];   // gate i
                const float4 qb = wqt[(4 + j) * 4];   // gate f
                const int ko = 4 * (s + 8 * j);
#pragma unroll
                for (int b = 0; b < 8; ++b) {
                    const float4 h4 = *(const float4*)&lhh[b][ko];  // broadcast, conflict-free
                    DOT4(va[b], qa, h4);
                    DOT4(vb[b], qb, h4);
                }
            }
            float Aa[4], Ab[4];
#pragma unroll
            for (int i = 0; i < 4; ++i) {
                Aa[i] = (f4 ? va[i+4] : va[i]) + dppf<0x141>(f4 ? va[i] : va[i+4]);
                Ab[i] = (f4 ? vb[i+4] : vb[i]) + dppf<0x141>(f4 ? vb[i] : vb[i+4]);
            }
            float Ba[2], Bb[2];
#pragma unroll
            for (int i = 0; i < 2; ++i) {
                Ba[i] = (f2 ? Aa[i+2] : Aa[i]) + dppf<0x4E>(f2 ? Aa[i] : Aa[i+2]);
                Bb[i] = (f2 ? Ab[i+2] : Ab[i]) + dppf<0x4E>(f2 ? Ab[i] : Ab[i+2]);
            }
            ri  = (f1 ? Ba[1] : Ba[0]) + dppf<0xB1>(f1 ? Ba[0] : Ba[1]);
            rf_ = (f1 ? Bb[1] : Bb[0]) + dppf<0xB1>(f1 ? Bb[0] : Bb[1]);
        }
        __builtin_amdgcn_sched_barrier(0);   // keep pass B's loads out of pass A

        // ======== layer 1, pass B: gates g,o ========
        float rg, ro;
        {
            float va[8], vb[8];
#pragma unroll
            for (int b = 0; b < 8; ++b) { va[b] = vb[b] = 0.0f; }
#pragma unroll
            for (int j = 0; j < 4; ++j) {
                const float4 qa = wqt[(8  + j) * 4];  // gate g
                const float4 qb = wqt[(12 + j) * 4];  // gate o
                const int ko = 4 * (s + 8 * j);
#pragma unroll
                for (int b = 0; b < 8; ++b) {
                    const float4 h4 = *(const float4*)&lhh[b][ko];
                    DOT4(va[b], qa, h4);
                    DOT4(vb[b], qb, h4);
                }
            }
            float Aa[4], Ab[4];
#pragma unroll
            for (int i = 0; i < 4; ++i) {
                Aa[i] = (f4 ? va[i+4] : va[i]) + dppf<0x141>(f4 ? va[i] : va[i+4]);
                Ab[i] = (f4 ? vb[i+4] : vb[i]) + dppf<0x141>(f4 ? vb[i] : vb[i+4]);
            }
            float Ba[2], Bb[2];
#pragma unroll
            for (int i = 0; i < 2; ++i) {
                Ba[i] = (f2 ? Aa[i+2] : Aa[i]) + dppf<0x4E>(f2 ? Aa[i] : Aa[i+2]);
                Bb[i] = (f2 ? Ab[i+2] : Ab[i]) + dppf<0x4E>(f2 ? Ab[i] : Ab[i+2]);
            }
            rg = (f1 ? Ba[1] : Ba[0]) + dppf<0xB1>(f1 ? Ba[0] : Ba[1]);
            ro = (f1 ? Bb[1] : Bb[0]) + dppf<0xB1>(f1 ? Bb[0] : Bb[1]);
        }
        __builtin_amdgcn_sched_barrier(0);

        // elementwise for (b = s, d) — all 1024 threads are owners.
        // Wih1 from LDS each step; opaque zero index defeats LICM hoisting.
        int zr; asm volatile("v_mov_b32 %0, 0" : "=v"(zr));
        const float4 wv0 = lwih4[0][d + zr];
        const float4 wv1 = lwih4[1][d + zr];
        const float x0 = lx[s][t], x1 = lx[s][TSTEPS + t];
        const float gi = ri  + wv0.x * x0 + wv0.y * x1;
        const float gf = rf_ + wv0.z * x0 + wv0.w * x1;
        const float gg = rg  + wv1.x * x0 + wv1.y * x1;
        const float go = ro  + wv1.z * x0 + wv1.w * x1;
        const float i1 = sigm(gi), ff = sigm(gf), g1v = tanhf_(gg), o1 = sigm(go);
        c1 = ff * c1 + i1 * g1v;
        const float h1n = o1 * tanhf_(c1);

        __syncthreads();                 // A: all reads of old h1 done
        lhh[s][d] = h1n;
        __syncthreads();                 // B: new h1 visible

        const bool g8 = (s2 & 8) != 0;
        const bool e4 = (s2 & 4) != 0;
        const bool e2 = (s2 & 2) != 0;
        const bool e1 = (s2 & 1) != 0;

        // ======== layer 2, pass A: gates i,f over K=192 slice s2 ========
        float DA, EA;
        {
            float ua[8], ub[8];
#pragma unroll
            for (int b = 0; b < 8; ++b) { ua[b] = ub[b] = 0.0f; }
#pragma unroll
            for (int j = 0; j < 3; ++j) {
                const float4 pa = wqt[(16 + j) * 4];  // gate i
                const float4 pb = wqt[(19 + j) * 4];  // gate f
                const int ko = 4 * (s2 + 16 * j);
#pragma unroll
                for (int b = 0; b < 8; ++b) {
                    const float4 h4 = *(const float4*)&lhh[b][ko];
                    DOT4(ua[b], pa, h4);
                    DOT4(ub[b], pb, h4);
                }
            }
            float T[8];
#pragma unroll
            for (int b = 0; b < 8; ++b)
                T[b] = (g8 ? ub[b] : ua[b]) + dppf<0x128>(g8 ? ua[b] : ub[b]);
            float V[4];
#pragma unroll
            for (int i = 0; i < 4; ++i)
                V[i] = (e4 ? T[i+4] : T[i]) + dppf<0x141>(e4 ? T[i] : T[i+4]);
            float X[2];
#pragma unroll
            for (int i = 0; i < 2; ++i)
                X[i] = (e2 ? V[i+2] : V[i]) + dppf<0x4E>(e2 ? V[i] : V[i+2]);
            DA = (e1 ? X[1] : X[0]) + dppf<0xB1>(e1 ? X[0] : X[1]);
            EA = dppf<0x128>(DA);
        }
        __builtin_amdgcn_sched_barrier(0);

        // ======== layer 2, pass B: gates g,o ========
        float DB, EB;
        {
            float ua[8], ub[8];
#pragma unroll
            for (int b = 0; b < 8; ++b) { ua[b] = ub[b] = 0.0f; }
#pragma unroll
            for (int j = 0; j < 3; ++j) {
                const float4 pa = wqt[(22 + j) * 4];  // gate g
                const float4 pb = wqt[(25 + j) * 4];  // gate o
                const int ko = 4 * (s2 + 16 * j);
#pragma unroll
                for (int b = 0; b < 8; ++b) {
                    const float4 h4 = *(const float4*)&lhh[b][ko];
                    DOT4(ua[b], pa, h4);
                    DOT4(ub[b], pb, h4);
                }
            }
            float T[8];
#pragma unroll
            for (int b = 0; b < 8; ++b)
                T[b] = (g8 ? ub[b] : ua[b]) + dppf<0x128>(g8 ? ua[b] : ub[b]);
            float V[4];
#pragma unroll
            for (int i = 0; i < 4; ++i)
                V[i] = (e4 ? T[i+4] : T[i]) + dppf<0x141>(e4 ? T[i] : T[i+4]);
            float X[2];
#pragma unroll
            for (int i = 0; i < 2; ++i)
                X[i] = (e2 ? V[i+2] : V[i]) + dppf<0x4E>(e2 ? V[i] : V[i+2]);
            DB = (e1 ? X[1] : X[0]) + dppf<0xB1>(e1 ? X[0] : X[1]);
            EB = dppf<0x128>(DB);
        }
        // lanes s2<8: i=DA, f=EA, g=DB, o=EB; lanes s2>=8: i=EA, f=DA, g=EB, o=DB (b = s2&7)

        const float gi2 = lowh ? DA : EA;
        const float gf2 = lowh ? EA : DA;
        const float gg2 = lowh ? DB : EB;
        const float go2 = lowh ? EB : DB;
        const float i2 = sigm(gi2), f2g = sigm(gf2), g2v = tanhf_(gg2), o2 = sigm(go2);
        c2 = f2g * c2 + i2 * g2v;                 // both lane-halves keep identical c2
        const float h2n = o2 * tanhf_(c2);
        // fused FC into LDS accumulators, classes split: lower lanes 0..5, upper 6..10
        if (packed) {
            const float* fp = wfcPk + (t << 10);
            const float4 fa = *(const float4*)fp;
            const float2 fb = *(const float2*)(fp + 4);
            lfacc[tid][0] += h2n * fa.x;
            lfacc[tid][1] += h2n * fa.y;
            lfacc[tid][2] += h2n * fa.z;
            lfacc[tid][3] += h2n * fa.w;
            lfacc[tid][4] += h2n * fb.x;
            if (lowh) lfacc[tid][5] += h2n * fb.y;
        } else {
            const float* wfcp = Wfc + t * 64 + d2 + (lowh ? 0 : 6 * 8192);
            if (lowh) {
#pragma unroll
                for (int c = 0; c < 6; ++c) lfacc[tid][c] += h2n * wfcp[c * 8192];
            } else {
#pragma unroll
                for (int c = 0; c < 5; ++c) lfacc[tid][c] += h2n * wfcp[c * 8192];
            }
        }
        __syncthreads();                 // C: all h1-new / h2-old reads done
        if (lowh) lhh[s2][128 + d2] = h2n;   // disjoint from next iter's h1 reads
    }

    // final FC reduction: pull per-thread accumulators back to regs, sum over the
    // 4 in-wave d2 groups (lane bits 4,5 — cross-row, keep __shfl_xor), then
    // across the 16 waves via LDS.
    float facc[6];
#pragma unroll
    for (int c = 0; c < 6; ++c) facc[c] = lfacc[tid][c];
#pragma unroll
    for (int c = 0; c < 6; ++c) {
        facc[c] += __shfl_xor(facc[c], 16);
        facc[c] += __shfl_xor(facc[c], 32);
    }
    const int wv = tid >> 6;
    if ((tid & 63) < 16) {
        const int bb = tid & 7;
        if ((tid & 15) < 8) {
#pragma unroll
            for (int c = 0; c < 6; ++c) fpart[wv][bb][c] = facc[c];
        } else {
#pragma unroll
            for (int c = 0; c < 5; ++c) fpart[wv][bb][6 + c] = facc[c];
        }
    }
    __syncthreads();
    if (tid < BTILE * NCLS) {
        const int bb = tid / NCLS, c = tid - bb * NCLS;
        float v = bfc[c];
#pragma unroll
        for (int w = 0; w < 16; ++w) v += fpart[w][bb][c];
        out[(b0 + bb) * NCLS + c] = v;
    }
}

extern "C" void kernel_launch(void* const* d_in, const int* in_sizes, int n_in,
                              void* d_out, int out_size, void* d_ws, size_t ws_size,
                              hipStream_t stream) {
    const float* x    = (const float*)d_in[0];
    const float* Wih1 = (const float*)d_in[1];
    const float* Whh1 = (const float*)d_in[2];
    const float* Wih2 = (const float*)d_in[3];
    const float* Whh2 = (const float*)d_in[4];
    const float* Wfc  = (const float*)d_in[5];
    const float* bfc  = (const float*)d_in[6];
    float* out = (float*)d_out;
    float* ws  = (float*)d_ws;

    const int packed = (ws_size >= (size_t)(WTOT + WFCF) * 4) ? 1 : 0;
    const int prep_elems = WTOT + (packed ? WFCF : 0);   // 448 KB (+512 KB packed FC)
    prep_weights<<<(prep_elems + 255) / 256, 256, 0, stream>>>(Whh1, Wih2, Whh2, Wfc, ws, packed);
    lstm_fused_t<<<256, 1024, 0, stream>>>(x, Wih1, Wfc, bfc, ws, out, packed);
}

// Round 11
// 1215.040 us; speedup vs baseline: 2.9772x; 1.1132x over previous
//
#include <hip/hip_runtime.h>

// Problem constants
#define TSTEPS 128
#define NCLS 11
#define BTILE 8
// ws layout (floats):
//  [0, WTOT): quad-interleaved weights: idx = (tid>>2)*448 + chunk*16 + (tid&3)*4 + kk
//    chunk 0..15  (L1): g = chunk>>2 (gate), j = chunk&3, s = tid&7, d = tid>>3,
//                       val = Whh1[(g*128+d)*128 + 4*(s+8j)+kk]
//    chunk 16..27 (L2): c2 = chunk-16, g = c2/3, j = c2%3, s = tid&15, d2 = tid>>4,
//                       col = 4*(s+16j)+kk; col<128 -> Wih2[g*64+d2][col] else Whh2[...][col-128]
//    => in-kernel: ONE base address/thread, all loads at immediate offset chunk*64B.
//  [WTOT, WTOT+WFCF): packed FC weights wsF[t][d2][16]:
//    slots 0..5 = Wfc[0..5][t*64+d2], slots 8..12 = Wfc[6..10][t*64+d2] (rest 0)
#define WTOT 114688
#define WFCF 131072

__device__ __forceinline__ float rcpf_(float x) { return __builtin_amdgcn_rcpf(x); }
// v_rcp_f32-based (1 ULP) — IEEE '/' emits an ~11-op div sequence without fast-math.
__device__ __forceinline__ float sigm(float x) { return rcpf_(1.0f + __expf(-x)); }
__device__ __forceinline__ float tanhf_(float x) { return 1.0f - 2.0f * rcpf_(__expf(2.0f * x) + 1.0f); }

// DPP lane exchange on VALU.
// ctrl: 0xB1 = quad_perm[1,0,3,2] (xor1), 0x4E = quad_perm[2,3,0,1] (xor2),
//       0x141 = row_half_mirror (p <-> 7-p within each 8; flips lane bit2),
//       0x128 = row_ror:8 (c <-> c^8 within each 16).
template <int CTRL>
__device__ __forceinline__ float dppf(float x) {
    return __int_as_float(__builtin_amdgcn_update_dpp(
        0, __float_as_int(x), CTRL, 0xF, 0xF, true));
}

__global__ void prep_weights(const float* __restrict__ Whh1,
                             const float* __restrict__ Wih2,
                             const float* __restrict__ Whh2,
                             const float* __restrict__ Wfc,
                             float* __restrict__ ws, int packFc) {
    int idx = blockIdx.x * blockDim.x + threadIdx.x;
    if (idx < WTOT) {
        int q = idx / 448;
        int r = idx % 448;
        int chunk = r >> 4;
        int lane = (r >> 2) & 3;
        int kk = idx & 3;
        int tid = q * 4 + lane;
        float v;
        if (chunk < 16) {
            int s = tid & 7, dd = tid >> 3, g = chunk >> 2, j = chunk & 3;
            v = Whh1[(g * 128 + dd) * 128 + 4 * (s + 8 * j) + kk];
        } else {
            int c2 = chunk - 16;
            int g = c2 / 3, j = c2 - 3 * g;
            int s = tid & 15, d2 = tid >> 4;
            int col = 4 * (s + 16 * j) + kk;
            int row = g * 64 + d2;
            v = (col < 128) ? Wih2[row * 128 + col] : Whh2[row * 64 + (col - 128)];
        }
        ws[idx] = v;
    } else if (packFc && idx < WTOT + WFCF) {
        int r = idx - WTOT;
        int t = r >> 10;
        int rem = r & 1023;
        int d2 = rem >> 4, slot = rem & 15;
        float v = 0.0f;
        if (slot < 6) v = Wfc[slot * 8192 + t * 64 + d2];
        else if (slot >= 8 && slot <= 12) v = Wfc[(slot - 2) * 8192 + t * 64 + d2];
        ws[idx] = v;
    }
}

#define DOT4(acc, q, h) (acc += (q).x*(h).x + (q).y*(h).y + (q).z*(h).z + (q).w*(h).w)

// Persistent fused 2-layer LSTM + FC. grid=256 (1 block/CU), block=1024 (16 waves).
// r1-r10 established: immovable 64-VGPR budget -> gate-pair split MACs, Wih1 +
// FC accums in LDS, single weight base + immediate offsets, DPP butterflies.
// Scratch = 0 (FETCH ~5 MB = inputs). Cycle math r10: VALU ~11K + DS ~7K +
// VMEM-TA ~7K per CU-step vs 27.8K measured -> pipes additive, not overlapped:
// 3 barriers/step re-convoy all 16 waves (loads burst together, MACs together).
// r11: (a) double-buffered lh1/lh2 -> ONE barrier/step. Race audit: in the
// drift window [B(t),B(t+1)) writes = {lh2[tb], lh1[xb]}, reads = {lh1[tb],
// lh2[xb]} — disjoint. (b) IEEE div -> v_rcp_f32 in sigm/tanh (10 divs/step
// were ~11 ops each).
__global__ __attribute__((amdgpu_flat_work_group_size(1024, 1024),
                          amdgpu_waves_per_eu(4, 4)))
void lstm_fused_t(const float* __restrict__ x, const float* __restrict__ Wih1,
                  const float* __restrict__ Wfc, const float* __restrict__ bfc,
                  const float* __restrict__ ws, float* __restrict__ out, int packed) {

    __shared__ __align__(16) float lx[BTILE][2 * TSTEPS + 4];  // x staged [b][c*128+t]
    __shared__ __align__(16) float lh1[2][BTILE][128];         // h1 double buffer
    __shared__ __align__(16) float lh2[2][BTILE][64];          // h2 double buffer
    __shared__ __align__(16) float4 lwih4[2][128];             // [0][d]=(ia,ib,fa,fb) [1][d]=(ga,gb,oa,ob)
    __shared__ float lfacc[1024][7];                           // per-thread FC accumulators (6 used)
    __shared__ float fpart[16][BTILE][NCLS];                   // per-wave FC partials (epilogue)

    const int tid = threadIdx.x;
    const int b0 = blockIdx.x * BTILE;

    for (int i = tid; i < BTILE * 2 * TSTEPS; i += 1024)
        lx[i >> 8][i & 255] = x[b0 * 256 + i];
    for (int i = tid; i < 2 * BTILE * 128; i += 1024)
        ((float*)lh1)[i] = 0.0f;
    if (tid < 2 * BTILE * 64) ((float*)lh2)[tid] = 0.0f;
    for (int i = tid; i < 1024 * 7; i += 1024)
        ((float*)lfacc)[i] = 0.0f;
    if (tid < 128) {
        const float2* wp = (const float2*)Wih1;   // row r -> float2 at index r
        const float2 ri = wp[tid], rf = wp[128 + tid], rg = wp[256 + tid], ro = wp[384 + tid];
        lwih4[0][tid] = make_float4(ri.x, ri.y, rf.x, rf.y);
        lwih4[1][tid] = make_float4(rg.x, rg.y, ro.x, ro.y);
    }

    const int d  = tid >> 3;
    const int s  = tid & 7;
    const int d2 = tid >> 4;
    const int s2 = tid & 15;
    const bool lowh = (s2 < 8);

    // single weight base: all 28 chunk loads at immediate offset chunk*64 bytes
    const float4* __restrict__ wqt = (const float4*)ws + ((tid >> 2) * 112 + (tid & 3));
    const float* __restrict__ wfcPk = ws + WTOT + ((d2 << 4) + (lowh ? 0 : 8));

    float c1 = 0.0f, c2 = 0.0f;

    __syncthreads();

#pragma unroll 1
    for (int t = 0; t < TSTEPS; ++t) {
        const int tb = t & 1;        // h_t buffer
        const int xb = tb ^ 1;       // h_{t-1} buffer
        const bool f4 = (s & 4) != 0;
        const bool f2 = (s & 2) != 0;
        const bool f1 = (s & 1) != 0;

        // ======== layer 1, pass A: gates i,f over K-slice s (16 accumulators) ========
        float ri, rf_;
        {
            float va[8], vb[8];
#pragma unroll
            for (int b = 0; b < 8; ++b) { va[b] = vb[b] = 0.0f; }
#pragma unroll
            for (int j = 0; j < 4; ++j) {
                const float4 qa = wqt[(0 + j) * 4];   // gate i
                const float4 qb = wqt[(4 + j) * 4];   // gate f
                const int ko = 4 * (s + 8 * j);
#pragma unroll
                for (int b = 0; b < 8; ++b) {
                    const float4 h4 = *(const float4*)&lh1[xb][b][ko];  // broadcast, conflict-free
                    DOT4(va[b], qa, h4);
                    DOT4(vb[b], qb, h4);
                }
            }
            float Aa[4], Ab[4];
#pragma unroll
            for (int i = 0; i < 4; ++i) {
                Aa[i] = (f4 ? va[i+4] : va[i]) + dppf<0x141>(f4 ? va[i] : va[i+4]);
                Ab[i] = (f4 ? vb[i+4] : vb[i]) + dppf<0x141>(f4 ? vb[i] : vb[i+4]);
            }
            float Ba[2], Bb[2];
#pragma unroll
            for (int i = 0; i < 2; ++i) {
                Ba[i] = (f2 ? Aa[i+2] : Aa[i]) + dppf<0x4E>(f2 ? Aa[i] : Aa[i+2]);
                Bb[i] = (f2 ? Ab[i+2] : Ab[i]) + dppf<0x4E>(f2 ? Ab[i] : Ab[i+2]);
            }
            ri  = (f1 ? Ba[1] : Ba[0]) + dppf<0xB1>(f1 ? Ba[0] : Ba[1]);
            rf_ = (f1 ? Bb[1] : Bb[0]) + dppf<0xB1>(f1 ? Bb[0] : Bb[1]);
        }
        __builtin_amdgcn_sched_barrier(0);   // keep pass B's loads out of pass A

        // ======== layer 1, pass B: gates g,o ========
        float rg, ro;
        {
            float va[8], vb[8];
#pragma unroll
            for (int b = 0; b < 8; ++b) { va[b] = vb[b] = 0.0f; }
#pragma unroll
            for (int j = 0; j < 4; ++j) {
                const float4 qa = wqt[(8  + j) * 4];  // gate g
                const float4 qb = wqt[(12 + j) * 4];  // gate o
                const int ko = 4 * (s + 8 * j);
#pragma unroll
                for (int b = 0; b < 8; ++b) {
                    const float4 h4 = *(const float4*)&lh1[xb][b][ko];
                    DOT4(va[b], qa, h4);
                    DOT4(vb[b], qb, h4);
                }
            }
            float Aa[4], Ab[4];
#pragma unroll
            for (int i = 0; i < 4; ++i) {
                Aa[i] = (f4 ? va[i+4] : va[i]) + dppf<0x141>(f4 ? va[i] : va[i+4]);
                Ab[i] = (f4 ? vb[i+4] : vb[i]) + dppf<0x141>(f4 ? vb[i] : vb[i+4]);
            }
            float Ba[2], Bb[2];
#pragma unroll
            for (int i = 0; i < 2; ++i) {
                Ba[i] = (f2 ? Aa[i+2] : Aa[i]) + dppf<0x4E>(f2 ? Aa[i] : Aa[i+2]);
                Bb[i] = (f2 ? Ab[i+2] : Ab[i]) + dppf<0x4E>(f2 ? Ab[i] : Ab[i+2]);
            }
            rg = (f1 ? Ba[1] : Ba[0]) + dppf<0xB1>(f1 ? Ba[0] : Ba[1]);
            ro = (f1 ? Bb[1] : Bb[0]) + dppf<0xB1>(f1 ? Bb[0] : Bb[1]);
        }
        __builtin_amdgcn_sched_barrier(0);

        // elementwise for (b = s, d) — all 1024 threads are owners.
        // Wih1 from LDS each step; opaque zero index defeats LICM hoisting.
        int zr; asm volatile("v_mov_b32 %0, 0" : "=v"(zr));
        const float4 wv0 = lwih4[0][d + zr];
        const float4 wv1 = lwih4[1][d + zr];
        const float x0 = lx[s][t], x1 = lx[s][TSTEPS + t];
        const float gi = ri  + wv0.x * x0 + wv0.y * x1;
        const float gf = rf_ + wv0.z * x0 + wv0.w * x1;
        const float gg = rg  + wv1.x * x0 + wv1.y * x1;
        const float go = ro  + wv1.z * x0 + wv1.w * x1;
        const float i1 = sigm(gi), ff = sigm(gf), g1v = tanhf_(gg), o1 = sigm(go);
        c1 = ff * c1 + i1 * g1v;
        const float h1n = o1 * tanhf_(c1);

        lh1[tb][s][d] = h1n;             // double-buffered: no pre-write barrier needed
        __syncthreads();                 // B: h1_t visible (the ONLY barrier per step)

        const bool g8 = (s2 & 8) != 0;
        const bool e4 = (s2 & 4) != 0;
        const bool e2 = (s2 & 2) != 0;
        const bool e1 = (s2 & 1) != 0;

        // ======== layer 2, pass A: gates i,f over K=192 slice s2 ========
        float DA, EA;
        {
            float ua[8], ub[8];
#pragma unroll
            for (int b = 0; b < 8; ++b) { ua[b] = ub[b] = 0.0f; }
#pragma unroll
            for (int j = 0; j < 3; ++j) {
                const float4 pa = wqt[(16 + j) * 4];  // gate i
                const float4 pb = wqt[(19 + j) * 4];  // gate f
#pragma unroll
                for (int b = 0; b < 8; ++b) {
                    const float4 h4 = (j < 2)
                        ? *(const float4*)&lh1[tb][b][4 * s2 + 64 * j]
                        : *(const float4*)&lh2[xb][b][4 * s2];
                    DOT4(ua[b], pa, h4);
                    DOT4(ub[b], pb, h4);
                }
            }
            float T[8];
#pragma unroll
            for (int b = 0; b < 8; ++b)
                T[b] = (g8 ? ub[b] : ua[b]) + dppf<0x128>(g8 ? ua[b] : ub[b]);
            float V[4];
#pragma unroll
            for (int i = 0; i < 4; ++i)
                V[i] = (e4 ? T[i+4] : T[i]) + dppf<0x141>(e4 ? T[i] : T[i+4]);
            float X[2];
#pragma unroll
            for (int i = 0; i < 2; ++i)
                X[i] = (e2 ? V[i+2] : V[i]) + dppf<0x4E>(e2 ? V[i] : V[i+2]);
            DA = (e1 ? X[1] : X[0]) + dppf<0xB1>(e1 ? X[0] : X[1]);
            EA = dppf<0x128>(DA);
        }
        __builtin_amdgcn_sched_barrier(0);

        // ======== layer 2, pass B: gates g,o ========
        float DB, EB;
        {
            float ua[8], ub[8];
#pragma unroll
            for (int b = 0; b < 8; ++b) { ua[b] = ub[b] = 0.0f; }
#pragma unroll
            for (int j = 0; j < 3; ++j) {
                const float4 pa = wqt[(22 + j) * 4];  // gate g
                const float4 pb = wqt[(25 + j) * 4];  // gate o
#pragma unroll
                for (int b = 0; b < 8; ++b) {
                    const float4 h4 = (j < 2)
                        ? *(const float4*)&lh1[tb][b][4 * s2 + 64 * j]
                        : *(const float4*)&lh2[xb][b][4 * s2];
                    DOT4(ua[b], pa, h4);
                    DOT4(ub[b], pb, h4);
                }
            }
            float T[8];
#pragma unroll
            for (int b = 0; b < 8; ++b)
                T[b] = (g8 ? ub[b] : ua[b]) + dppf<0x128>(g8 ? ua[b] : ub[b]);
            float V[4];
#pragma unroll
            for (int i = 0; i < 4; ++i)
                V[i] = (e4 ? T[i+4] : T[i]) + dppf<0x141>(e4 ? T[i] : T[i+4]);
            float X[2];
#pragma unroll
            for (int i = 0; i < 2; ++i)
                X[i] = (e2 ? V[i+2] : V[i]) + dppf<0x4E>(e2 ? V[i] : V[i+2]);
            DB = (e1 ? X[1] : X[0]) + dppf<0xB1>(e1 ? X[0] : X[1]);
            EB = dppf<0x128>(DB);
        }
        // lanes s2<8: i=DA, f=EA, g=DB, o=EB; lanes s2>=8: i=EA, f=DA, g=EB, o=DB (b = s2&7)

        const float gi2 = lowh ? DA : EA;
        const float gf2 = lowh ? EA : DA;
        const float gg2 = lowh ? DB : EB;
        const float go2 = lowh ? EB : DB;
        const float i2 = sigm(gi2), f2g = sigm(gf2), g2v = tanhf_(gg2), o2 = sigm(go2);
        c2 = f2g * c2 + i2 * g2v;                 // both lane-halves keep identical c2
        const float h2n = o2 * tanhf_(c2);
        // fused FC into LDS accumulators, classes split: lower lanes 0..5, upper 6..10
        if (packed) {
            const float* fp = wfcPk + (t << 10);
            const float4 fa = *(const float4*)fp;
            const float2 fb = *(const float2*)(fp + 4);
            lfacc[tid][0] += h2n * fa.x;
            lfacc[tid][1] += h2n * fa.y;
            lfacc[tid][2] += h2n * fa.z;
            lfacc[tid][3] += h2n * fa.w;
            lfacc[tid][4] += h2n * fb.x;
            if (lowh) lfacc[tid][5] += h2n * fb.y;
        } else {
            const float* wfcp = Wfc + t * 64 + d2 + (lowh ? 0 : 6 * 8192);
            if (lowh) {
#pragma unroll
                for (int c = 0; c < 6; ++c) lfacc[tid][c] += h2n * wfcp[c * 8192];
            } else {
#pragma unroll
                for (int c = 0; c < 5; ++c) lfacc[tid][c] += h2n * wfcp[c * 8192];
            }
        }
        if (lowh) lh2[tb][s2][d2] = h2n;   // double-buffered: next read is after B(t+1)
    }

    // final FC reduction: pull per-thread accumulators back to regs, sum over the
    // 4 in-wave d2 groups (lane bits 4,5 — cross-row, keep __shfl_xor), then
    // across the 16 waves via LDS.
    float facc[6];
#pragma unroll
    for (int c = 0; c < 6; ++c) facc[c] = lfacc[tid][c];
#pragma unroll
    for (int c = 0; c < 6; ++c) {
        facc[c] += __shfl_xor(facc[c], 16);
        facc[c] += __shfl_xor(facc[c], 32);
    }
    const int wv = tid >> 6;
    if ((tid & 63) < 16) {
        const int bb = tid & 7;
        if ((tid & 15) < 8) {
#pragma unroll
            for (int c = 0; c < 6; ++c) fpart[wv][bb][c] = facc[c];
        } else {
#pragma unroll
            for (int c = 0; c < 5; ++c) fpart[wv][bb][6 + c] = facc[c];
        }
    }
    __syncthreads();
    if (tid < BTILE * NCLS) {
        const int bb = tid / NCLS, c = tid - bb * NCLS;
        float v = bfc[c];
#pragma unroll
        for (int w = 0; w < 16; ++w) v += fpart[w][bb][c];
        out[(b0 + bb) * NCLS + c] = v;
    }
}

extern "C" void kernel_launch(void* const* d_in, const int* in_sizes, int n_in,
                              void* d_out, int out_size, void* d_ws, size_t ws_size,
                              hipStream_t stream) {
    const float* x    = (const float*)d_in[0];
    const float* Wih1 = (const float*)d_in[1];
    const float* Whh1 = (const float*)d_in[2];
    const float* Wih2 = (const float*)d_in[3];
    const float* Whh2 = (const float*)d_in[4];
    const float* Wfc  = (const float*)d_in[5];
    const float* bfc  = (const float*)d_in[6];
    float* out = (float*)d_out;
    float* ws  = (float*)d_ws;

    const int packed = (ws_size >= (size_t)(WTOT + WFCF) * 4) ? 1 : 0;
    const int prep_elems = WTOT + (packed ? WFCF : 0);   // 448 KB (+512 KB packed FC)
    prep_weights<<<(prep_elems + 255) / 256, 256, 0, stream>>>(Whh1, Wih2, Whh2, Wfc, ws, packed);
    lstm_fused_t<<<256, 1024, 0, stream>>>(x, Wih1, Wfc, bfc, ws, out, packed);
}